// Round 9
// baseline (1345.307 us; speedup 1.0000x reference)
//
#include <hip/hip_runtime.h>
#include <hip/hip_cooperative_groups.h>
#include <math.h>

#define EPS 1e-5f
#define FD 8192
#define GRID 768

namespace cg = cooperative_groups;

typedef __attribute__((ext_vector_type(8))) __bf16 bf16x8;
typedef __attribute__((ext_vector_type(4))) float f32x4;

static __device__ __forceinline__ f32x4 mfma16(bf16x8 a, bf16x8 b, f32x4 c) {
    return __builtin_amdgcn_mfma_f32_16x16x32_bf16(a, b, c, 0, 0, 0);
}

struct MegaArgs {
    const float *inA, *inP, *inN;
    const float *bn0g, *bn0b, *bn0m, *bn0v;
    const float *w1, *w2, *b1;
    const float *bn1g, *bn1b, *bn1m, *bn1v;
    const float *b2, *bn2g, *bn2b, *bn2m, *bn2v;
    const float *lc1, *lc2;
    const float *bn3g, *bn3b, *bn3m, *bn3v;
    const float *bn4g, *bn4b, *bn4m, *bn4v;
    const float *fc1w, *fc1b, *g1, *bb1, *m1, *v1;
    const float *fc2w, *fc2b, *g2, *bb2, *m2, *v2;
    const float *fc3w, *fc3b, *g3, *bb3, *m3, *v3;
    const float *outw, *outb;
    __bf16 *w1frag, *w2frag, *lc1frag, *lc2frag, *fc1Wb, *wf23, *act, *act3;
    float *part;
    float *dout;
};

// ================= persistent cooperative mega-kernel ========================
// stages: prep -> conv -> lc -> fc1 -> reduce -> fc2 -> fc3out, grid.sync()
// between. 768 blocks (3/CU), LDS union 34304 B.
__global__ __launch_bounds__(256, 3) void k_mega(MegaArgs A) {
    cg::grid_group gg = cg::this_grid();
    const int bid = blockIdx.x;
    const int t = threadIdx.x;
    __shared__ __align__(16) char smem[34304];

    const int lane = t & 63, w = t >> 6;
    const int q = lane >> 4, li = lane & 15;

    // ---------------- stage P: all weight prep (2003 virtual blocks) --------
    for (int vb = bid; vb < 2003; vb += GRID) {
        __syncthreads();
        if (vb == 0) {
            const int o = w * 16 + li;
            bf16x8 v;
#pragma unroll
            for (int j = 0; j < 8; ++j) {
                int k = q * 8 + j;
                v[j] = (k < 9) ? (__bf16)A.w1[o * 9 + k] : (__bf16)0.0f;
            }
            *(bf16x8*)(A.w1frag + t * 8) = v;
        } else if (vb < 19) {
            const int id = (vb - 1) * 256 + t;
            const int ln = id & 63;
            const int ww = (id >> 6) & 3;
            const int chunk = (id >> 8) & 1;
            const int tap = id >> 9;
            const int qq = ln >> 4, ll = ln & 15;
            const int o = ww * 16 + ll;
            const int c0 = chunk * 32 + qq * 8;
            bf16x8 v;
#pragma unroll
            for (int j = 0; j < 8; ++j)
                v[j] = (__bf16)A.w2[(o * 64 + c0 + j) * 9 + tap];
            *(bf16x8*)(A.w2frag + (size_t)id * 8) = v;
        } else if (vb < 147) {
            float (*wbuf)[66] = (float(*)[66])smem;
            const int bx = vb - 19;
            const int layer = bx >> 6, o = bx & 63;
            const int wo = o >> 4, lo = o & 15;
            const float* src = (layer ? A.lc2 : A.lc1) + (size_t)o * 8192;
            __bf16* dst = layer ? A.lc2frag : A.lc1frag;
            for (int P = 0; P < 2; ++P) {
                if (P) __syncthreads();
#pragma unroll
                for (int it = 0; it < 4; ++it) {
                    int idx = it * 1024 + t * 4;
                    int c = idx >> 6, pp = idx & 63;
                    float4 v = *(const float4*)(src + c * 128 + P * 64 + pp);
                    wbuf[c][pp + 0] = v.x; wbuf[c][pp + 1] = v.y;
                    wbuf[c][pp + 2] = v.z; wbuf[c][pp + 3] = v.w;
                }
                __syncthreads();
#pragma unroll
                for (int it = 0; it < 2; ++it) {
                    int slot = it * 256 + t;
                    int pp = slot >> 3, chunk = (slot >> 2) & 1, qq = slot & 3;
                    int p = P * 64 + pp;
                    bf16x8 v;
#pragma unroll
                    for (int j = 0; j < 8; ++j)
                        v[j] = (__bf16)wbuf[chunk * 32 + qq * 8 + j][pp];
                    *(bf16x8*)(dst + ((size_t)((p * 2 + chunk) * 4 + wo) * 64 + qq * 16 + lo) * 8) = v;
                }
            }
        } else if (vb < 659) {
            float (*wbuf)[66] = (float(*)[66])smem;
            const int n = vb - 147;
            const float* src = A.fc1w + (size_t)n * 8192;
            __bf16* dst = A.fc1Wb + (size_t)n * 8192;
            for (int P = 0; P < 2; ++P) {
                if (P) __syncthreads();
#pragma unroll
                for (int it = 0; it < 4; ++it) {
                    int idx = it * 1024 + t * 4;
                    int c = idx >> 6, pp = idx & 63;
                    float4 v = *(const float4*)(src + c * 128 + P * 64 + pp);
                    wbuf[c][pp + 0] = v.x; wbuf[c][pp + 1] = v.y;
                    wbuf[c][pp + 2] = v.z; wbuf[c][pp + 3] = v.w;
                }
                __syncthreads();
#pragma unroll
                for (int it = 0; it < 8; ++it) {
                    int kA = P * 4096 + (it * 256 + t) * 2;
                    int c = kA & 63, pp = (kA >> 6) & 63;
                    __bf16 tmp[2];
                    tmp[0] = (__bf16)wbuf[c][pp];
                    tmp[1] = (__bf16)wbuf[c + 1][pp];
                    *(unsigned int*)(dst + kA) = *(unsigned int*)tmp;
                }
            }
        } else {
            int i = (vb - 659) * 256 + t;
            float v;
            if (i < 262144) v = A.fc2w[i];
            else if (i < 327680) v = A.fc3w[i - 262144];
            else v = A.outw[i - 327680];
            A.wf23[i] = (__bf16)v;
        }
    }
    __threadfence();
    gg.sync();

    // ---------------- stage C: conv (1536 virtual, 2 per block) -------------
    {
        __bf16* Xp  = (__bf16*)smem;                 // 31104 B
        float* xpad = (float*)(smem + 31104);        // 768 B
        float* s1   = (float*)(smem + 31872);
        float* sh1  = (float*)(smem + 32128);
        float* s2   = (float*)(smem + 32384);
        float* sh2  = (float*)(smem + 32640);
        const int n0 = w * 16;

        for (int b = bid; b < 1536; b += GRID) {
            __syncthreads();
            const float* src = (b < 512 ? A.inA : (b < 1024 ? A.inP : A.inN))
                               + (size_t)(b & 511) * 128;
            bf16x8 w1f = *(const bf16x8*)(A.w1frag + (size_t)(w * 64 + lane) * 8);
            bf16x8 w2f[18];
#pragma unroll
            for (int tap = 0; tap < 9; ++tap)
#pragma unroll
                for (int ch = 0; ch < 2; ++ch)
                    w2f[tap * 2 + ch] = *(const bf16x8*)(A.w2frag +
                        ((size_t)((tap * 2 + ch) * 4 + w) * 64 + lane) * 8);
            {
                int* xz = (int*)Xp;
                for (int i = t; i < 7776; i += 256) xz[i] = 0;
                if (t < 180) xpad[t] = 0.f;
                if (t < 64) {
                    float sa = A.bn1g[t] * rsqrtf(A.bn1v[t] + EPS);
                    s1[t] = sa;
                    sh1[t] = (A.b1[t] - A.bn1m[t]) * sa + A.bn1b[t];
                    float sb = A.bn2g[t] * rsqrtf(A.bn2v[t] + EPS);
                    s2[t] = sb;
                    sh2[t] = (A.b2[t] - A.bn2m[t]) * sb + A.bn2b[t];
                }
            }
            __syncthreads();
            if (t < 128) {
                float s0 = A.bn0g[0] * rsqrtf(A.bn0v[0] + EPS);
                float v = (src[t] - A.bn0m[0]) * s0 + A.bn0b[0];
                xpad[((t >> 3) + 1) * 10 + (t & 7) + 1] = v;
            }
            __syncthreads();
            {   // conv1 MFMA, A-frag direct from xpad
                const float sco = s1[n0 + li], sho = sh1[n0 + li];
                const int o = n0 + li;
#pragma unroll
                for (int m = 0; m < 8; ++m) {
                    const int p = m * 16 + li;
                    const int r = p >> 3, cl = p & 7;
                    bf16x8 a;
#pragma unroll
                    for (int j = 0; j < 8; ++j) a[j] = (__bf16)0.f;
                    if (q == 0) {
                        const float* xb = xpad + r * 10 + cl;
                        a[0] = (__bf16)xb[0];  a[1] = (__bf16)xb[1];  a[2] = (__bf16)xb[2];
                        a[3] = (__bf16)xb[10]; a[4] = (__bf16)xb[11]; a[5] = (__bf16)xb[12];
                        a[6] = (__bf16)xb[20]; a[7] = (__bf16)xb[21];
                    } else if (q == 1) {
                        a[0] = (__bf16)xpad[(r + 2) * 10 + cl + 2];
                    }
                    f32x4 z = {0.f, 0.f, 0.f, 0.f};
                    f32x4 d = mfma16(a, w1f, z);
#pragma unroll
                    for (int r2 = 0; r2 < 4; ++r2) {
                        int pp = m * 16 + q * 4 + r2;
                        float v = fmaxf(d[r2] * sco + sho, 0.f);
                        Xp[(((pp >> 3) + 1) * 12 + (pp & 7) + 1) * 72 + o] = (__bf16)v;
                    }
                }
            }
            __syncthreads();
            f32x4 accA[4], accB[4];
#pragma unroll
            for (int i = 0; i < 4; ++i) {
                accA[i] = (f32x4){0.f, 0.f, 0.f, 0.f};
                accB[i] = (f32x4){0.f, 0.f, 0.f, 0.f};
            }
            {
                const int cl = li & 7;
#pragma unroll
                for (int mp = 0; mp < 4; ++mp) {
                    const int r0 = mp * 4 + (li >> 3);
                    const int base0 = (r0 * 12 + cl) * 72 + q * 8;
                    const int base1 = base0 + 1728;
#pragma unroll
                    for (int tap = 0; tap < 9; ++tap) {
                        const int tofs = ((tap / 3) * 12 + (tap % 3)) * 72;
#pragma unroll
                        for (int ch = 0; ch < 2; ++ch) {
                            bf16x8 a0 = *(const bf16x8*)&Xp[base0 + tofs + ch * 32];
                            bf16x8 a1 = *(const bf16x8*)&Xp[base1 + tofs + ch * 32];
                            accA[mp] = mfma16(a0, w2f[tap * 2 + ch], accA[mp]);
                            accB[mp] = mfma16(a1, w2f[tap * 2 + ch], accB[mp]);
                        }
                    }
                }
            }
            __syncthreads();
            {
                const float sco = s2[n0 + li], sho = sh2[n0 + li];
                const int o = n0 + li;
#pragma unroll
                for (int mp = 0; mp < 4; ++mp) {
#pragma unroll
                    for (int r = 0; r < 4; ++r) {
                        int p0 = mp * 32 + q * 4 + r;
                        Xp[p0 * 72 + o] = (__bf16)fmaxf(accA[mp][r] * sco + sho, 0.f);
                        Xp[(p0 + 16) * 72 + o] = (__bf16)fmaxf(accB[mp][r] * sco + sho, 0.f);
                    }
                }
            }
            __syncthreads();
            {
                int p = t >> 1, half = t & 1;
                const __bf16* rp = Xp + p * 72 + half * 32;
                __bf16* ob = A.act + (size_t)b * FD + p * 64 + half * 32;
                bf16x8 v0 = *(const bf16x8*)rp;
                bf16x8 v1 = *(const bf16x8*)(rp + 8);
                bf16x8 v2 = *(const bf16x8*)(rp + 16);
                bf16x8 v3 = *(const bf16x8*)(rp + 24);
                *(bf16x8*)ob = v0;
                *(bf16x8*)(ob + 8) = v1;
                *(bf16x8*)(ob + 16) = v2;
                *(bf16x8*)(ob + 24) = v3;
            }
        }
    }
    __threadfence();
    gg.sync();

    // ---------------- stage L: lc (3072 virtual, 4 per block) ---------------
    {
        __bf16* xs = (__bf16*)smem;                  // 9216 B
        __bf16* ys = (__bf16*)(smem + 9216);         // 9216 B
        float* s3  = (float*)(smem + 18432);
        float* sh3 = (float*)(smem + 18688);
        float* s4  = (float*)(smem + 18944);
        float* sh4 = (float*)(smem + 19200);
        const int n0 = w * 16;

        for (int vb = bid; vb < 3072; vb += GRID) {
            __syncthreads();
            const int p = vb & 127;
            const int b0 = (vb >> 7) * 64;
            if (t < 64) {
                float sa = A.bn3g[t] * rsqrtf(A.bn3v[t] + EPS);
                s3[t] = sa; sh3[t] = A.bn3b[t] - A.bn3m[t] * sa;
                float sb = A.bn4g[t] * rsqrtf(A.bn4v[t] + EPS);
                s4[t] = sb; sh4[t] = A.bn4b[t] - A.bn4m[t] * sb;
            }
            {
                int s = t >> 2, cg2 = t & 3;
                const __bf16* rp = A.act + (size_t)(b0 + s) * FD + p * 64 + cg2 * 16;
                *(bf16x8*)&xs[s * 72 + cg2 * 16] = *(const bf16x8*)rp;
                *(bf16x8*)&xs[s * 72 + cg2 * 16 + 8] = *(const bf16x8*)(rp + 8);
            }
            bf16x8 w1a = *(const bf16x8*)(A.lc1frag + ((size_t)((p * 2 + 0) * 4 + w) * 64 + lane) * 8);
            bf16x8 w1b = *(const bf16x8*)(A.lc1frag + ((size_t)((p * 2 + 1) * 4 + w) * 64 + lane) * 8);
            bf16x8 w2a = *(const bf16x8*)(A.lc2frag + ((size_t)((p * 2 + 0) * 4 + w) * 64 + lane) * 8);
            bf16x8 w2b = *(const bf16x8*)(A.lc2frag + ((size_t)((p * 2 + 1) * 4 + w) * 64 + lane) * 8);
            __syncthreads();
            {
                const float sco = s3[n0 + li], sho = sh3[n0 + li];
#pragma unroll
                for (int m = 0; m < 4; ++m) {
                    bf16x8 a0 = *(const bf16x8*)&xs[(m * 16 + li) * 72 + q * 8];
                    bf16x8 a1 = *(const bf16x8*)&xs[(m * 16 + li) * 72 + 32 + q * 8];
                    f32x4 acc = {0.f, 0.f, 0.f, 0.f};
                    acc = mfma16(a0, w1a, acc);
                    acc = mfma16(a1, w1b, acc);
#pragma unroll
                    for (int r = 0; r < 4; ++r) {
                        int bl = m * 16 + q * 4 + r;
                        ys[bl * 72 + n0 + li] = (__bf16)fmaxf(acc[r] * sco + sho, 0.f);
                    }
                }
            }
            __syncthreads();
            {
                const float sco = s4[n0 + li], sho = sh4[n0 + li];
#pragma unroll
                for (int m = 0; m < 4; ++m) {
                    bf16x8 a0 = *(const bf16x8*)&ys[(m * 16 + li) * 72 + q * 8];
                    bf16x8 a1 = *(const bf16x8*)&ys[(m * 16 + li) * 72 + 32 + q * 8];
                    f32x4 acc = {0.f, 0.f, 0.f, 0.f};
                    acc = mfma16(a0, w2a, acc);
                    acc = mfma16(a1, w2b, acc);
#pragma unroll
                    for (int r = 0; r < 4; ++r) {
                        int bl = m * 16 + q * 4 + r;
                        xs[bl * 72 + n0 + li] = (__bf16)fmaxf(acc[r] * sco + sho, 0.f);
                    }
                }
            }
            __syncthreads();
            {
                int s = t >> 2, cg2 = t & 3;
                const __bf16* rp = xs + s * 72 + cg2 * 16;
                __bf16* ob = A.act + (size_t)(b0 + s) * FD + p * 64 + cg2 * 16;
                bf16x8 v0 = *(const bf16x8*)rp;
                bf16x8 v1 = *(const bf16x8*)(rp + 8);
                *(bf16x8*)ob = v0;
                *(bf16x8*)(ob + 8) = v1;
            }
        }
    }
    __threadfence();
    gg.sync();

    // ---------------- stage F1: fc1 split-K 8 (768 virtual = grid) ----------
    {
        __bf16 (*As)[64 * 40] = (__bf16(*)[64 * 40])smem;            // 10240 B
        __bf16 (*Bs)[128 * 40] = (__bf16(*)[128 * 40])(smem + 10240); // 20480 B
        const int bx = bid % 24, rest = bid / 24;
        const int by = rest & 3, bz = rest >> 2;
        const int m0 = bx * 64, n0 = by * 128, k0 = bz * 1024;
        const int wm = (w & 1) * 32, wn = (w >> 1) * 64;

        __syncthreads();
        f32x4 acc[2][4];
#pragma unroll
        for (int i = 0; i < 2; ++i)
#pragma unroll
            for (int j = 0; j < 4; ++j) acc[i][j] = (f32x4){0.f, 0.f, 0.f, 0.f};

        const int rowA = (t & 127) >> 1, rowB = t >> 1, half = t & 1;
        const __bf16* Ag = A.act + (size_t)(m0 + rowA) * 8192 + k0 + half * 16;
        const __bf16* Bg = A.fc1Wb + (size_t)(n0 + rowB) * 8192 + k0 + half * 16;

        bf16x8 pa0, pa1, pb0, pb1;
        pb0 = *(const bf16x8*)Bg;
        pb1 = *(const bf16x8*)(Bg + 8);
        if (t < 128) {
            pa0 = *(const bf16x8*)Ag;
            pa1 = *(const bf16x8*)(Ag + 8);
        }
        for (int step = 0; step < 32; ++step) {
            const int cur = step & 1;
            if (t < 128) {
                *(bf16x8*)&As[cur][rowA * 40 + half * 16] = pa0;
                *(bf16x8*)&As[cur][rowA * 40 + half * 16 + 8] = pa1;
            }
            *(bf16x8*)&Bs[cur][rowB * 40 + half * 16] = pb0;
            *(bf16x8*)&Bs[cur][rowB * 40 + half * 16 + 8] = pb1;
            __syncthreads();
            Ag += 32; Bg += 32;
            if (step < 31) {
                pb0 = *(const bf16x8*)Bg;
                pb1 = *(const bf16x8*)(Bg + 8);
                if (t < 128) {
                    pa0 = *(const bf16x8*)Ag;
                    pa1 = *(const bf16x8*)(Ag + 8);
                }
            }
            bf16x8 af[2], bfr[4];
#pragma unroll
            for (int i = 0; i < 2; ++i)
                af[i] = *(const bf16x8*)&As[cur][(wm + i * 16 + li) * 40 + q * 8];
#pragma unroll
            for (int j = 0; j < 4; ++j)
                bfr[j] = *(const bf16x8*)&Bs[cur][(wn + j * 16 + li) * 40 + q * 8];
#pragma unroll
            for (int i = 0; i < 2; ++i)
#pragma unroll
                for (int j = 0; j < 4; ++j)
                    acc[i][j] = mfma16(af[i], bfr[j], acc[i][j]);
        }
        float* pp = A.part + (size_t)bz * 786432;
#pragma unroll
        for (int i = 0; i < 2; ++i) {
#pragma unroll
            for (int r = 0; r < 4; ++r) {
                int m = m0 + wm + i * 16 + q * 4 + r;
#pragma unroll
                for (int j = 0; j < 4; ++j) {
                    int n = n0 + wn + j * 16 + li;
                    pp[(size_t)m * 512 + n] = acc[i][j][r];
                }
            }
        }
    }
    __threadfence();
    gg.sync();

    // ---------------- stage R: reduce (768 virtual = grid) ------------------
    {
        int gi = bid * 256 + t;
        size_t off = (size_t)gi * 4;
        float4 s = make_float4(0.f, 0.f, 0.f, 0.f);
#pragma unroll
        for (int z = 0; z < 8; ++z) {
            float4 v = *(const float4*)(A.part + (size_t)z * 786432 + off);
            s.x += v.x; s.y += v.y; s.z += v.z; s.w += v.w;
        }
        int n = (gi & 127) * 4;
        float r4[4] = {s.x, s.y, s.z, s.w};
        __bf16 o4[4];
#pragma unroll
        for (int j = 0; j < 4; ++j) {
            float sc = A.g1[n + j] * rsqrtf(A.v1[n + j] + EPS);
            float x = (r4[j] + A.fc1b[n + j] - A.m1[n + j]) * sc + A.bb1[n + j];
            o4[j] = (__bf16)fmaxf(x, 0.f);
        }
        *(uint2*)(A.act3 + off) = *(uint2*)o4;
    }
    __threadfence();
    gg.sync();

    // ---------------- stage F2: fc2 (192 virtual) ---------------------------
    if (bid < 192) {
        __bf16 (*As)[64 * 40] = (__bf16(*)[64 * 40])smem;
        __bf16 (*Bs)[64 * 40] = (__bf16(*)[64 * 40])(smem + 10240);
        const __bf16* W = A.wf23;                    // fc2 weights
        __bf16* outp = A.act3 + 786432;              // act4 slot right after act3
        const int m0 = (bid % 24) * 64, n0 = (bid / 24) * 64;
        const int wm = (w & 1) * 32, wn = (w >> 1) * 32;
        const int K = 512, N = 512;

        __syncthreads();
        f32x4 acc[2][2];
#pragma unroll
        for (int i = 0; i < 2; ++i)
#pragma unroll
            for (int j = 0; j < 2; ++j) acc[i][j] = (f32x4){0.f, 0.f, 0.f, 0.f};

        const int row = (t & 127) >> 1, half = t & 1;
        const __bf16* g = (t < 128 ? A.act3 + (size_t)(m0 + row) * K
                                   : W + (size_t)(n0 + row) * K) + half * 16;
        const int ldo = row * 40 + half * 16;
        bf16x8 p0 = *(const bf16x8*)g;
        bf16x8 p1 = *(const bf16x8*)(g + 8);
        for (int s = 0; s < 16; ++s) {
            const int cur = s & 1;
            __bf16* ld = (t < 128 ? As[cur] : Bs[cur]) + ldo;
            *(bf16x8*)ld = p0;
            *(bf16x8*)(ld + 8) = p1;
            __syncthreads();
            g += 32;
            if (s < 15) {
                p0 = *(const bf16x8*)g;
                p1 = *(const bf16x8*)(g + 8);
            }
            bf16x8 af[2], bfr[2];
#pragma unroll
            for (int i = 0; i < 2; ++i)
                af[i] = *(const bf16x8*)&As[cur][(wm + i * 16 + li) * 40 + q * 8];
#pragma unroll
            for (int j = 0; j < 2; ++j)
                bfr[j] = *(const bf16x8*)&Bs[cur][(wn + j * 16 + li) * 40 + q * 8];
#pragma unroll
            for (int i = 0; i < 2; ++i)
#pragma unroll
                for (int j = 0; j < 2; ++j)
                    acc[i][j] = mfma16(af[i], bfr[j], acc[i][j]);
        }
        float bi[2], sc[2], hh[2];
#pragma unroll
        for (int j = 0; j < 2; ++j) {
            int n = n0 + wn + j * 16 + li;
            bi[j] = A.fc2b[n];
            sc[j] = A.g2[n] * rsqrtf(A.v2[n] + EPS);
            hh[j] = A.bb2[n] - A.m2[n] * sc[j];
        }
#pragma unroll
        for (int i = 0; i < 2; ++i) {
#pragma unroll
            for (int r = 0; r < 4; ++r) {
                int m = m0 + wm + i * 16 + q * 4 + r;
#pragma unroll
                for (int j = 0; j < 2; ++j) {
                    int n = n0 + wn + j * 16 + li;
                    float x = (acc[i][j][r] + bi[j]) * sc[j] + hh[j];
                    outp[(size_t)m * N + n] = (__bf16)fmaxf(x, 0.f);
                }
            }
        }
    }
    __threadfence();
    gg.sync();

    // ---------------- stage F3: fc3 + out (48 virtual) ----------------------
    if (bid < 48) {
        __bf16 (*As)[32 * 40] = (__bf16(*)[32 * 40])smem;             // 5120 B
        __bf16 (*Bs)[128 * 40] = (__bf16(*)[128 * 40])(smem + 5120);  // 20480 B
        __bf16* ysb = (__bf16*)(smem + 25600);                        // 8704 B
        const __bf16* Aact4 = A.act3 + 786432;
        const __bf16* W3 = A.wf23 + 262144;
        const __bf16* Wo = A.wf23 + 327680;
        const int m0 = bid * 32;
        const int wn = w * 32;

        __syncthreads();
        const int rowA = (t & 63) >> 1, rowB = t >> 1, half = t & 1;
        const __bf16* Ag = Aact4 + (size_t)(m0 + rowA) * 512 + half * 16;
        const __bf16* Bg = W3 + (size_t)rowB * 512 + half * 16;

        f32x4 acc[2][2];
#pragma unroll
        for (int i = 0; i < 2; ++i)
#pragma unroll
            for (int j = 0; j < 2; ++j) acc[i][j] = (f32x4){0.f, 0.f, 0.f, 0.f};

        bf16x8 pa0, pa1, pb0, pb1;
        pb0 = *(const bf16x8*)Bg;
        pb1 = *(const bf16x8*)(Bg + 8);
        if (t < 64) {
            pa0 = *(const bf16x8*)Ag;
            pa1 = *(const bf16x8*)(Ag + 8);
        }
        for (int step = 0; step < 16; ++step) {
            const int cur = step & 1;
            if (t < 64) {
                *(bf16x8*)&As[cur][rowA * 40 + half * 16] = pa0;
                *(bf16x8*)&As[cur][rowA * 40 + half * 16 + 8] = pa1;
            }
            *(bf16x8*)&Bs[cur][rowB * 40 + half * 16] = pb0;
            *(bf16x8*)&Bs[cur][rowB * 40 + half * 16 + 8] = pb1;
            __syncthreads();
            Ag += 32; Bg += 32;
            if (step < 15) {
                pb0 = *(const bf16x8*)Bg;
                pb1 = *(const bf16x8*)(Bg + 8);
                if (t < 64) {
                    pa0 = *(const bf16x8*)Ag;
                    pa1 = *(const bf16x8*)(Ag + 8);
                }
            }
            bf16x8 af[2], bfr[2];
#pragma unroll
            for (int i = 0; i < 2; ++i)
                af[i] = *(const bf16x8*)&As[cur][(i * 16 + li) * 40 + q * 8];
#pragma unroll
            for (int j = 0; j < 2; ++j)
                bfr[j] = *(const bf16x8*)&Bs[cur][(wn + j * 16 + li) * 40 + q * 8];
#pragma unroll
            for (int i = 0; i < 2; ++i)
#pragma unroll
                for (int j = 0; j < 2; ++j)
                    acc[i][j] = mfma16(af[i], bfr[j], acc[i][j]);
        }
        __syncthreads();
        {
#pragma unroll
            for (int j = 0; j < 2; ++j) {
                int n = wn + j * 16 + li;
                float sc = A.g3[n] * rsqrtf(A.v3[n] + EPS);
                float hh = A.bb3[n] - A.m3[n] * sc;
                float bi = A.fc3b[n];
#pragma unroll
                for (int i = 0; i < 2; ++i)
#pragma unroll
                    for (int r = 0; r < 4; ++r) {
                        int ml = i * 16 + q * 4 + r;
                        float x = (acc[i][j][r] + bi) * sc + hh;
                        ysb[ml * 136 + n] = (__bf16)fmaxf(x, 0.f);
                    }
            }
        }
        __syncthreads();
        f32x4 acc2[2][2];
#pragma unroll
        for (int i = 0; i < 2; ++i)
#pragma unroll
            for (int j = 0; j < 2; ++j) acc2[i][j] = (f32x4){0.f, 0.f, 0.f, 0.f};
        const __bf16* Bg2 = Wo + (size_t)rowB * 128 + half * 16;
#pragma unroll
        for (int s = 0; s < 4; ++s) {
            const int cur = s & 1;
            *(bf16x8*)&Bs[cur][rowB * 40 + half * 16] = *(const bf16x8*)(Bg2 + s * 32);
            *(bf16x8*)&Bs[cur][rowB * 40 + half * 16 + 8] = *(const bf16x8*)(Bg2 + s * 32 + 8);
            __syncthreads();
            bf16x8 af[2], bfr[2];
#pragma unroll
            for (int i = 0; i < 2; ++i)
                af[i] = *(const bf16x8*)&ysb[(i * 16 + li) * 136 + s * 32 + q * 8];
#pragma unroll
            for (int j = 0; j < 2; ++j)
                bfr[j] = *(const bf16x8*)&Bs[cur][(wn + j * 16 + li) * 40 + q * 8];
#pragma unroll
            for (int i = 0; i < 2; ++i)
#pragma unroll
                for (int j = 0; j < 2; ++j)
                    acc2[i][j] = mfma16(af[i], bfr[j], acc2[i][j]);
        }
#pragma unroll
        for (int j = 0; j < 2; ++j) {
            int n = wn + j * 16 + li;
            float bi = A.outb[n];
#pragma unroll
            for (int i = 0; i < 2; ++i)
#pragma unroll
                for (int r = 0; r < 4; ++r) {
                    int m = m0 + i * 16 + q * 4 + r;
                    A.dout[(size_t)m * 128 + n] = acc2[i][j][r] + bi;
                }
        }
    }
}

// ======================= fallback path (proven r7/r8 kernels) ================
__global__ __launch_bounds__(256) void k_prep_conv(
    const float* __restrict__ w1, const float* __restrict__ w2,
    __bf16* __restrict__ w1frag, __bf16* __restrict__ w2frag) {
    const int bb = blockIdx.x;
    const int t = threadIdx.x;
    if (bb == 0) {
        const int lane = t & 63, w = t >> 6;
        const int q = lane >> 4, li = lane & 15;
        const int o = w * 16 + li;
        bf16x8 v;
#pragma unroll
        for (int j = 0; j < 8; ++j) {
            int k = q * 8 + j;
            v[j] = (k < 9) ? (__bf16)w1[o * 9 + k] : (__bf16)0.0f;
        }
        *(bf16x8*)(w1frag + t * 8) = v;
    } else {
        const int id = (bb - 1) * 256 + t;
        const int lane = id & 63;
        const int w = (id >> 6) & 3;
        const int chunk = (id >> 8) & 1;
        const int tap = id >> 9;
        const int q = lane >> 4, li = lane & 15;
        const int o = w * 16 + li;
        const int c0 = chunk * 32 + q * 8;
        bf16x8 v;
#pragma unroll
        for (int j = 0; j < 8; ++j)
            v[j] = (__bf16)w2[(o * 64 + c0 + j) * 9 + tap];
        *(bf16x8*)(w2frag + (size_t)id * 8) = v;
    }
}

__global__ __launch_bounds__(256) void k_conv_prep(
    const float* __restrict__ inA, const float* __restrict__ inP, const float* __restrict__ inN,
    const float* __restrict__ bn0g, const float* __restrict__ bn0b,
    const float* __restrict__ bn0m, const float* __restrict__ bn0v,
    const __bf16* __restrict__ w1frag, const float* __restrict__ b1,
    const float* __restrict__ bn1g, const float* __restrict__ bn1b,
    const float* __restrict__ bn1m, const float* __restrict__ bn1v,
    const __bf16* __restrict__ w2frag, const float* __restrict__ b2,
    const float* __restrict__ bn2g, const float* __restrict__ bn2b,
    const float* __restrict__ bn2m, const float* __restrict__ bn2v,
    __bf16* __restrict__ act,
    const float* __restrict__ lc1, const float* __restrict__ lc2,
    const float* __restrict__ fc1w, const float* __restrict__ fc2w,
    const float* __restrict__ fc3w, const float* __restrict__ outw,
    __bf16* __restrict__ lc1frag, __bf16* __restrict__ lc2frag,
    __bf16* __restrict__ fc1Wb, __bf16* __restrict__ wf23) {
    const int bb = blockIdx.x;
    const int t = threadIdx.x;
    __shared__ __align__(16) char smem[32896];

    if (bb >= 1536) {
        const int bx2 = bb - 1536;
        if (bx2 < 128) {
            float (*wbuf)[66] = (float(*)[66])smem;
            const int layer = bx2 >> 6, o = bx2 & 63;
            const int wo = o >> 4, lo = o & 15;
            const float* src = (layer ? lc2 : lc1) + (size_t)o * 8192;
            __bf16* dst = layer ? lc2frag : lc1frag;
            for (int P = 0; P < 2; ++P) {
                if (P) __syncthreads();
#pragma unroll
                for (int it = 0; it < 4; ++it) {
                    int idx = it * 1024 + t * 4;
                    int c = idx >> 6, pp = idx & 63;
                    float4 v = *(const float4*)(src + c * 128 + P * 64 + pp);
                    wbuf[c][pp + 0] = v.x; wbuf[c][pp + 1] = v.y;
                    wbuf[c][pp + 2] = v.z; wbuf[c][pp + 3] = v.w;
                }
                __syncthreads();
#pragma unroll
                for (int it = 0; it < 2; ++it) {
                    int slot = it * 256 + t;
                    int pp = slot >> 3, chunk = (slot >> 2) & 1, q = slot & 3;
                    int p = P * 64 + pp;
                    bf16x8 v;
#pragma unroll
                    for (int j = 0; j < 8; ++j)
                        v[j] = (__bf16)wbuf[chunk * 32 + q * 8 + j][pp];
                    *(bf16x8*)(dst + ((size_t)((p * 2 + chunk) * 4 + wo) * 64 + q * 16 + lo) * 8) = v;
                }
            }
        } else if (bx2 < 640) {
            float (*wbuf)[66] = (float(*)[66])smem;
            const int n = bx2 - 128;
            const float* src = fc1w + (size_t)n * 8192;
            __bf16* dst = fc1Wb + (size_t)n * 8192;
            for (int P = 0; P < 2; ++P) {
                if (P) __syncthreads();
#pragma unroll
                for (int it = 0; it < 4; ++it) {
                    int idx = it * 1024 + t * 4;
                    int c = idx >> 6, pp = idx & 63;
                    float4 v = *(const float4*)(src + c * 128 + P * 64 + pp);
                    wbuf[c][pp + 0] = v.x; wbuf[c][pp + 1] = v.y;
                    wbuf[c][pp + 2] = v.z; wbuf[c][pp + 3] = v.w;
                }
                __syncthreads();
#pragma unroll
                for (int it = 0; it < 8; ++it) {
                    int kA = P * 4096 + (it * 256 + t) * 2;
                    int c = kA & 63, pp = (kA >> 6) & 63;
                    __bf16 tmp[2];
                    tmp[0] = (__bf16)wbuf[c][pp];
                    tmp[1] = (__bf16)wbuf[c + 1][pp];
                    *(unsigned int*)(dst + kA) = *(unsigned int*)tmp;
                }
            }
        } else {
            int i = (bx2 - 640) * 256 + t;
            float v;
            if (i < 262144) v = fc2w[i];
            else if (i < 327680) v = fc3w[i - 262144];
            else v = outw[i - 327680];
            wf23[i] = (__bf16)v;
        }
        return;
    }

    __bf16* Xp  = (__bf16*)smem;
    float* xpad = (float*)(smem + 31104);
    float* s1   = (float*)(smem + 31872);
    float* sh1  = (float*)(smem + 32128);
    float* s2   = (float*)(smem + 32384);
    float* sh2  = (float*)(smem + 32640);

    const int b = bb;
    const int lane = t & 63, w = t >> 6;
    const int q = lane >> 4, li = lane & 15;
    const int n0 = w * 16;
    const float* src = (b < 512 ? inA : (b < 1024 ? inP : inN)) + (size_t)(b & 511) * 128;

    bf16x8 w1f = *(const bf16x8*)(w1frag + (size_t)(w * 64 + lane) * 8);
    bf16x8 w2f[18];
#pragma unroll
    for (int tap = 0; tap < 9; ++tap)
#pragma unroll
        for (int ch = 0; ch < 2; ++ch)
            w2f[tap * 2 + ch] = *(const bf16x8*)(w2frag +
                ((size_t)((tap * 2 + ch) * 4 + w) * 64 + lane) * 8);

    {
        int* xz = (int*)Xp;
        for (int i = t; i < 7776; i += 256) xz[i] = 0;
        if (t < 180) xpad[t] = 0.f;
        if (t < 64) {
            float sa = bn1g[t] * rsqrtf(bn1v[t] + EPS);
            s1[t] = sa;
            sh1[t] = (b1[t] - bn1m[t]) * sa + bn1b[t];
            float sb = bn2g[t] * rsqrtf(bn2v[t] + EPS);
            s2[t] = sb;
            sh2[t] = (b2[t] - bn2m[t]) * sb + bn2b[t];
        }
    }
    __syncthreads();
    if (t < 128) {
        float s0 = bn0g[0] * rsqrtf(bn0v[0] + EPS);
        float v = (src[t] - bn0m[0]) * s0 + bn0b[0];
        xpad[((t >> 3) + 1) * 10 + (t & 7) + 1] = v;
    }
    __syncthreads();
    {
        const float sco = s1[n0 + li], sho = sh1[n0 + li];
        const int o = n0 + li;
#pragma unroll
        for (int m = 0; m < 8; ++m) {
            const int p = m * 16 + li;
            const int r = p >> 3, cl = p & 7;
            bf16x8 a;
#pragma unroll
            for (int j = 0; j < 8; ++j) a[j] = (__bf16)0.f;
            if (q == 0) {
                const float* xb = xpad + r * 10 + cl;
                a[0] = (__bf16)xb[0];  a[1] = (__bf16)xb[1];  a[2] = (__bf16)xb[2];
                a[3] = (__bf16)xb[10]; a[4] = (__bf16)xb[11]; a[5] = (__bf16)xb[12];
                a[6] = (__bf16)xb[20]; a[7] = (__bf16)xb[21];
            } else if (q == 1) {
                a[0] = (__bf16)xpad[(r + 2) * 10 + cl + 2];
            }
            f32x4 z = {0.f, 0.f, 0.f, 0.f};
            f32x4 d = mfma16(a, w1f, z);
#pragma unroll
            for (int r2 = 0; r2 < 4; ++r2) {
                int pp = m * 16 + q * 4 + r2;
                float v = fmaxf(d[r2] * sco + sho, 0.f);
                Xp[(((pp >> 3) + 1) * 12 + (pp & 7) + 1) * 72 + o] = (__bf16)v;
            }
        }
    }
    __syncthreads();
    f32x4 accA[4], accB[4];
#pragma unroll
    for (int i = 0; i < 4; ++i) {
        accA[i] = (f32x4){0.f, 0.f, 0.f, 0.f};
        accB[i] = (f32x4){0.f, 0.f, 0.f, 0.f};
    }
    {
        const int cl = li & 7;
#pragma unroll
        for (int mp = 0; mp < 4; ++mp) {
            const int r0 = mp * 4 + (li >> 3);
            const int base0 = (r0 * 12 + cl) * 72 + q * 8;
            const int base1 = base0 + 1728;
#pragma unroll
            for (int tap = 0; tap < 9; ++tap) {
                const int tofs = ((tap / 3) * 12 + (tap % 3)) * 72;
#pragma unroll
                for (int ch = 0; ch < 2; ++ch) {
                    bf16x8 a0 = *(const bf16x8*)&Xp[base0 + tofs + ch * 32];
                    bf16x8 a1 = *(const bf16x8*)&Xp[base1 + tofs + ch * 32];
                    accA[mp] = mfma16(a0, w2f[tap * 2 + ch], accA[mp]);
                    accB[mp] = mfma16(a1, w2f[tap * 2 + ch], accB[mp]);
                }
            }
        }
    }
    __syncthreads();
    {
        const float sco = s2[n0 + li], sho = sh2[n0 + li];
        const int o = n0 + li;
#pragma unroll
        for (int mp = 0; mp < 4; ++mp) {
#pragma unroll
            for (int r = 0; r < 4; ++r) {
                int p0 = mp * 32 + q * 4 + r;
                Xp[p0 * 72 + o] = (__bf16)fmaxf(accA[mp][r] * sco + sho, 0.f);
                Xp[(p0 + 16) * 72 + o] = (__bf16)fmaxf(accB[mp][r] * sco + sho, 0.f);
            }
        }
    }
    __syncthreads();
    {
        int p = t >> 1, half = t & 1;
        const __bf16* rp = Xp + p * 72 + half * 32;
        __bf16* ob = act + (size_t)b * FD + p * 64 + half * 32;
        bf16x8 v0 = *(const bf16x8*)rp;
        bf16x8 v1 = *(const bf16x8*)(rp + 8);
        bf16x8 v2 = *(const bf16x8*)(rp + 16);
        bf16x8 v3 = *(const bf16x8*)(rp + 24);
        *(bf16x8*)ob = v0;
        *(bf16x8*)(ob + 8) = v1;
        *(bf16x8*)(ob + 16) = v2;
        *(bf16x8*)(ob + 24) = v3;
    }
}

__global__ __launch_bounds__(256) void k_lc_mfma(
    const __bf16* __restrict__ lc1frag, const __bf16* __restrict__ lc2frag,
    const float* __restrict__ bn3g, const float* __restrict__ bn3b,
    const float* __restrict__ bn3m, const float* __restrict__ bn3v,
    const float* __restrict__ bn4g, const float* __restrict__ bn4b,
    const float* __restrict__ bn4m, const float* __restrict__ bn4v,
    __bf16* __restrict__ act) {
    const int p = blockIdx.x;
    const int b0 = blockIdx.y * 64;
    const int t = threadIdx.x;
    const int lane = t & 63, w = t >> 6;
    const int q = lane >> 4, li = lane & 15;
    const int n0 = w * 16;

    __shared__ __align__(16) __bf16 xs[64 * 72];
    __shared__ __align__(16) __bf16 ys[64 * 72];
    __shared__ float s3[64], sh3[64], s4[64], sh4[64];

    if (t < 64) {
        float sa = bn3g[t] * rsqrtf(bn3v[t] + EPS);
        s3[t] = sa; sh3[t] = bn3b[t] - bn3m[t] * sa;
        float sb = bn4g[t] * rsqrtf(bn4v[t] + EPS);
        s4[t] = sb; sh4[t] = bn4b[t] - bn4m[t] * sb;
    }
    {
        int s = t >> 2, cg2 = t & 3;
        const __bf16* rp = act + (size_t)(b0 + s) * FD + p * 64 + cg2 * 16;
        *(bf16x8*)&xs[s * 72 + cg2 * 16] = *(const bf16x8*)rp;
        *(bf16x8*)&xs[s * 72 + cg2 * 16 + 8] = *(const bf16x8*)(rp + 8);
    }
    bf16x8 w1a = *(const bf16x8*)(lc1frag + ((size_t)((p * 2 + 0) * 4 + w) * 64 + lane) * 8);
    bf16x8 w1b = *(const bf16x8*)(lc1frag + ((size_t)((p * 2 + 1) * 4 + w) * 64 + lane) * 8);
    bf16x8 w2a = *(const bf16x8*)(lc2frag + ((size_t)((p * 2 + 0) * 4 + w) * 64 + lane) * 8);
    bf16x8 w2b = *(const bf16x8*)(lc2frag + ((size_t)((p * 2 + 1) * 4 + w) * 64 + lane) * 8);
    __syncthreads();
    {
        const float sco = s3[n0 + li], sho = sh3[n0 + li];
#pragma unroll
        for (int m = 0; m < 4; ++m) {
            bf16x8 a0 = *(const bf16x8*)&xs[(m * 16 + li) * 72 + q * 8];
            bf16x8 a1 = *(const bf16x8*)&xs[(m * 16 + li) * 72 + 32 + q * 8];
            f32x4 acc = {0.f, 0.f, 0.f, 0.f};
            acc = mfma16(a0, w1a, acc);
            acc = mfma16(a1, w1b, acc);
#pragma unroll
            for (int r = 0; r < 4; ++r) {
                int bl = m * 16 + q * 4 + r;
                ys[bl * 72 + n0 + li] = (__bf16)fmaxf(acc[r] * sco + sho, 0.f);
            }
        }
    }
    __syncthreads();
    {
        const float sco = s4[n0 + li], sho = sh4[n0 + li];
#pragma unroll
        for (int m = 0; m < 4; ++m) {
            bf16x8 a0 = *(const bf16x8*)&ys[(m * 16 + li) * 72 + q * 8];
            bf16x8 a1 = *(const bf16x8*)&ys[(m * 16 + li) * 72 + 32 + q * 8];
            f32x4 acc = {0.f, 0.f, 0.f, 0.f};
            acc = mfma16(a0, w2a, acc);
            acc = mfma16(a1, w2b, acc);
#pragma unroll
            for (int r = 0; r < 4; ++r) {
                int bl = m * 16 + q * 4 + r;
                xs[bl * 72 + n0 + li] = (__bf16)fmaxf(acc[r] * sco + sho, 0.f);
            }
        }
    }
    __syncthreads();
    {
        int s = t >> 2, cg2 = t & 3;
        const __bf16* rp = xs + s * 72 + cg2 * 16;
        __bf16* ob = act + (size_t)(b0 + s) * FD + p * 64 + cg2 * 16;
        bf16x8 v0 = *(const bf16x8*)rp;
        bf16x8 v1 = *(const bf16x8*)(rp + 8);
        *(bf16x8*)ob = v0;
        *(bf16x8*)(ob + 8) = v1;
    }
}

__global__ __launch_bounds__(256) void k_fc1_mfma(
    const __bf16* __restrict__ A, const __bf16* __restrict__ Wb,
    float* __restrict__ part) {
    const int t = threadIdx.x;
    const int lane = t & 63, w = t >> 6;
    const int q = lane >> 4, li = lane & 15;
    const int m0 = blockIdx.x * 64, n0 = blockIdx.y * 128;
    const int k0 = blockIdx.z * 1024;
    const int wm = (w & 1) * 32, wn = (w >> 1) * 64;

    __shared__ __align__(16) __bf16 As[2][64 * 40];
    __shared__ __align__(16) __bf16 Bs[2][128 * 40];

    f32x4 acc[2][4];
#pragma unroll
    for (int i = 0; i < 2; ++i)
#pragma unroll
        for (int j = 0; j < 4; ++j) acc[i][j] = (f32x4){0.f, 0.f, 0.f, 0.f};

    const int rowA = (t & 127) >> 1, rowB = t >> 1, half = t & 1;
    const __bf16* Ag = A + (size_t)(m0 + rowA) * 8192 + k0 + half * 16;
    const __bf16* Bg = Wb + (size_t)(n0 + rowB) * 8192 + k0 + half * 16;

    bf16x8 pa0, pa1, pb0, pb1;
    pb0 = *(const bf16x8*)Bg;
    pb1 = *(const bf16x8*)(Bg + 8);
    if (t < 128) {
        pa0 = *(const bf16x8*)Ag;
        pa1 = *(const bf16x8*)(Ag + 8);
    }
    for (int step = 0; step < 32; ++step) {
        const int cur = step & 1;
        if (t < 128) {
            *(bf16x8*)&As[cur][rowA * 40 + half * 16] = pa0;
            *(bf16x8*)&As[cur][rowA * 40 + half * 16 + 8] = pa1;
        }
        *(bf16x8*)&Bs[cur][rowB * 40 + half * 16] = pb0;
        *(bf16x8*)&Bs[cur][rowB * 40 + half * 16 + 8] = pb1;
        __syncthreads();
        Ag += 32; Bg += 32;
        if (step < 31) {
            pb0 = *(const bf16x8*)Bg;
            pb1 = *(const bf16x8*)(Bg + 8);
            if (t < 128) {
                pa0 = *(const bf16x8*)Ag;
                pa1 = *(const bf16x8*)(Ag + 8);
            }
        }
        bf16x8 af[2], bfr[4];
#pragma unroll
        for (int i = 0; i < 2; ++i)
            af[i] = *(const bf16x8*)&As[cur][(wm + i * 16 + li) * 40 + q * 8];
#pragma unroll
        for (int j = 0; j < 4; ++j)
            bfr[j] = *(const bf16x8*)&Bs[cur][(wn + j * 16 + li) * 40 + q * 8];
#pragma unroll
        for (int i = 0; i < 2; ++i)
#pragma unroll
            for (int j = 0; j < 4; ++j)
                acc[i][j] = mfma16(af[i], bfr[j], acc[i][j]);
    }
    float* pp = part + (size_t)blockIdx.z * 786432;
#pragma unroll
    for (int i = 0; i < 2; ++i) {
#pragma unroll
        for (int r = 0; r < 4; ++r) {
            int m = m0 + wm + i * 16 + q * 4 + r;
#pragma unroll
            for (int j = 0; j < 4; ++j) {
                int n = n0 + wn + j * 16 + li;
                pp[(size_t)m * 512 + n] = acc[i][j][r];
            }
        }
    }
}

__global__ void k_fc1_reduce(const float* __restrict__ part, const float* __restrict__ bias,
                             const float* __restrict__ g, const float* __restrict__ bb,
                             const float* __restrict__ mm, const float* __restrict__ vv,
                             __bf16* __restrict__ out) {
    int gi = blockIdx.x * 256 + threadIdx.x;
    size_t off = (size_t)gi * 4;
    float4 s = make_float4(0.f, 0.f, 0.f, 0.f);
#pragma unroll
    for (int z = 0; z < 8; ++z) {
        float4 v = *(const float4*)(part + (size_t)z * 786432 + off);
        s.x += v.x; s.y += v.y; s.z += v.z; s.w += v.w;
    }
    int n = (gi & 127) * 4;
    float r[4] = {s.x, s.y, s.z, s.w};
    __bf16 o4[4];
#pragma unroll
    for (int j = 0; j < 4; ++j) {
        float sc = g[n + j] * rsqrtf(vv[n + j] + EPS);
        float x = (r[j] + bias[n + j] - mm[n + j]) * sc + bb[n + j];
        o4[j] = (__bf16)fmaxf(x, 0.f);
    }
    *(uint2*)(out + off) = *(uint2*)o4;
}

__global__ __launch_bounds__(256) void k_fc2_mfma(
    const __bf16* __restrict__ A, const __bf16* __restrict__ W,
    const float* __restrict__ bias,
    const float* __restrict__ bng, const float* __restrict__ bnb,
    const float* __restrict__ bnm, const float* __restrict__ bnv,
    __bf16* __restrict__ out) {
    const int t = threadIdx.x;
    const int lane = t & 63, w = t >> 6;
    const int q = lane >> 4, li = lane & 15;
    const int m0 = blockIdx.x * 64, n0 = blockIdx.y * 64;
    const int wm = (w & 1) * 32, wn = (w >> 1) * 32;
    const int K = 512, N = 512;

    __shared__ __align__(16) __bf16 As[2][64 * 40];
    __shared__ __align__(16) __bf16 Bs[2][64 * 40];

    f32x4 acc[2][2];
#pragma unroll
    for (int i = 0; i < 2; ++i)
#pragma unroll
        for (int j = 0; j < 2; ++j) acc[i][j] = (f32x4){0.f, 0.f, 0.f, 0.f};

    const int row = (t & 127) >> 1, half = t & 1;
    const __bf16* g = (t < 128 ? A + (size_t)(m0 + row) * K
                               : W + (size_t)(n0 + row) * K) + half * 16;
    const int ldo = row * 40 + half * 16;

    bf16x8 p0 = *(const bf16x8*)g;
    bf16x8 p1 = *(const bf16x8*)(g + 8);
    for (int s = 0; s < 16; ++s) {
        const int cur = s & 1;
        __bf16* ld = (t < 128 ? As[cur] : Bs[cur]) + ldo;
        *(bf16x8*)ld = p0;
        *(bf16x8*)(ld + 8) = p1;
        __syncthreads();
        g += 32;
        if (s < 15) {
            p0 = *(const bf16x8*)g;
            p1 = *(const bf16x8*)(g + 8);
        }
        bf16x8 af[2], bfr[2];
#pragma unroll
        for (int i = 0; i < 2; ++i)
            af[i] = *(const bf16x8*)&As[cur][(wm + i * 16 + li) * 40 + q * 8];
#pragma unroll
        for (int j = 0; j < 2; ++j)
            bfr[j] = *(const bf16x8*)&Bs[cur][(wn + j * 16 + li) * 40 + q * 8];
#pragma unroll
        for (int i = 0; i < 2; ++i)
#pragma unroll
            for (int j = 0; j < 2; ++j)
                acc[i][j] = mfma16(af[i], bfr[j], acc[i][j]);
    }
    float bi[2], sc[2], hh[2];
#pragma unroll
    for (int j = 0; j < 2; ++j) {
        int n = n0 + wn + j * 16 + li;
        bi[j] = bias[n];
        sc[j] = bng[n] * rsqrtf(bnv[n] + EPS);
        hh[j] = bnb[n] - bnm[n] * sc[j];
    }
#pragma unroll
    for (int i = 0; i < 2; ++i) {
#pragma unroll
        for (int r = 0; r < 4; ++r) {
            int m = m0 + wm + i * 16 + q * 4 + r;
#pragma unroll
            for (int j = 0; j < 2; ++j) {
                int n = n0 + wn + j * 16 + li;
                float x = (acc[i][j][r] + bi[j]) * sc[j] + hh[j];
                out[(size_t)m * N + n] = (__bf16)fmaxf(x, 0.f);
            }
        }
    }
}

__global__ __launch_bounds__(256) void k_fc3out(
    const __bf16* __restrict__ A, const __bf16* __restrict__ W3,
    const __bf16* __restrict__ Wo,
    const float* __restrict__ b3,
    const float* __restrict__ bng, const float* __restrict__ bnb,
    const float* __restrict__ bnm, const float* __restrict__ bnv,
    const float* __restrict__ bo, float* __restrict__ out) {
    const int t = threadIdx.x;
    const int lane = t & 63, w = t >> 6;
    const int q = lane >> 4, li = lane & 15;
    const int m0 = blockIdx.x * 32;
    const int wn = w * 32;

    __shared__ __align__(16) __bf16 As[2][32 * 40];
    __shared__ __align__(16) __bf16 Bs[2][128 * 40];
    __shared__ __align__(16) __bf16 ysb[32 * 136];

    const int rowA = (t & 63) >> 1, rowB = t >> 1, half = t & 1;
    const __bf16* Ag = A + (size_t)(m0 + rowA) * 512 + half * 16;
    const __bf16* Bg = W3 + (size_t)rowB * 512 + half * 16;

    f32x4 acc[2][2];
#pragma unroll
    for (int i = 0; i < 2; ++i)
#pragma unroll
        for (int j = 0; j < 2; ++j) acc[i][j] = (f32x4){0.f, 0.f, 0.f, 0.f};

    bf16x8 pa0, pa1, pb0, pb1;
    pb0 = *(const bf16x8*)Bg;
    pb1 = *(const bf16x8*)(Bg + 8);
    if (t < 64) {
        pa0 = *(const bf16x8*)Ag;
        pa1 = *(const bf16x8*)(Ag + 8);
    }
    for (int step = 0; step < 16; ++step) {
        const int cur = step & 1;
        if (t < 64) {
            *(bf16x8*)&As[cur][rowA * 40 + half * 16] = pa0;
            *(bf16x8*)&As[cur][rowA * 40 + half * 16 + 8] = pa1;
        }
        *(bf16x8*)&Bs[cur][rowB * 40 + half * 16] = pb0;
        *(bf16x8*)&Bs[cur][rowB * 40 + half * 16 + 8] = pb1;
        __syncthreads();
        Ag += 32; Bg += 32;
        if (step < 15) {
            pb0 = *(const bf16x8*)Bg;
            pb1 = *(const bf16x8*)(Bg + 8);
            if (t < 64) {
                pa0 = *(const bf16x8*)Ag;
                pa1 = *(const bf16x8*)(Ag + 8);
            }
        }
        bf16x8 af[2], bfr[2];
#pragma unroll
        for (int i = 0; i < 2; ++i)
            af[i] = *(const bf16x8*)&As[cur][(i * 16 + li) * 40 + q * 8];
#pragma unroll
        for (int j = 0; j < 2; ++j)
            bfr[j] = *(const bf16x8*)&Bs[cur][(wn + j * 16 + li) * 40 + q * 8];
#pragma unroll
        for (int i = 0; i < 2; ++i)
#pragma unroll
            for (int j = 0; j < 2; ++j)
                acc[i][j] = mfma16(af[i], bfr[j], acc[i][j]);
    }
    __syncthreads();
    {
#pragma unroll
        for (int j = 0; j < 2; ++j) {
            int n = wn + j * 16 + li;
            float sc = bng[n] * rsqrtf(bnv[n] + EPS);
            float hh = bnb[n] - bnm[n] * sc;
            float bi = b3[n];
#pragma unroll
            for (int i = 0; i < 2; ++i)
#pragma unroll
                for (int r = 0; r < 4; ++r) {
                    int ml = i * 16 + q * 4 + r;
                    float x = (acc[i][j][r] + bi) * sc + hh;
                    ysb[ml * 136 + n] = (__bf16)fmaxf(x, 0.f);
                }
        }
    }
    __syncthreads();
    f32x4 acc2[2][2];
#pragma unroll
    for (int i = 0; i < 2; ++i)
#pragma unroll
        for (int j = 0; j < 2; ++j) acc2[i][j] = (f32x4){0.f, 0.f, 0.f, 0.f};
    const __bf16* Bg2 = Wo + (size_t)rowB * 128 + half * 16;
#pragma unroll
    for (int s = 0; s < 4; ++s) {
        const int cur = s & 1;
        *(bf16x8*)&Bs[cur][rowB * 40 + half * 16] = *(const bf16x8*)(Bg2 + s * 32);
        *(bf16x8*)&Bs[cur][rowB * 40 + half * 16 + 8] = *(const bf16x8*)(Bg2 + s * 32 + 8);
        __syncthreads();
        bf16x8 af[2], bfr[2];
#pragma unroll
        for (int i = 0; i < 2; ++i)
            af[i] = *(const bf16x8*)&ysb[(i * 16 + li) * 136 + s * 32 + q * 8];
#pragma unroll
        for (int j = 0; j < 2; ++j)
            bfr[j] = *(const bf16x8*)&Bs[cur][(wn + j * 16 + li) * 40 + q * 8];
#pragma unroll
        for (int i = 0; i < 2; ++i)
#pragma unroll
            for (int j = 0; j < 2; ++j)
                acc2[i][j] = mfma16(af[i], bfr[j], acc2[i][j]);
    }
#pragma unroll
    for (int j = 0; j < 2; ++j) {
        int n = wn + j * 16 + li;
        float bi = bo[n];
#pragma unroll
        for (int i = 0; i < 2; ++i)
#pragma unroll
            for (int r = 0; r < 4; ++r) {
                int m = m0 + i * 16 + q * 4 + r;
                out[(size_t)m * 128 + n] = acc2[i][j][r] + bi;
            }
    }
}

extern "C" void kernel_launch(void* const* d_in, const int* in_sizes, int n_in,
                              void* d_out, int out_size, void* d_ws, size_t ws_size,
                              hipStream_t stream) {
    const float* inA    = (const float*)d_in[0];
    const float* inP    = (const float*)d_in[1];
    const float* inN    = (const float*)d_in[2];
    const float* bn0g   = (const float*)d_in[3];
    const float* bn0b   = (const float*)d_in[4];
    const float* bn0m   = (const float*)d_in[5];
    const float* bn0v   = (const float*)d_in[6];
    const float* conv1w = (const float*)d_in[7];
    const float* conv1b = (const float*)d_in[8];
    const float* bn1g   = (const float*)d_in[9];
    const float* bn1b   = (const float*)d_in[10];
    const float* bn1m   = (const float*)d_in[11];
    const float* bn1v   = (const float*)d_in[12];
    const float* conv2w = (const float*)d_in[13];
    const float* conv2b = (const float*)d_in[14];
    const float* bn2g   = (const float*)d_in[15];
    const float* bn2b   = (const float*)d_in[16];
    const float* bn2m   = (const float*)d_in[17];
    const float* bn2v   = (const float*)d_in[18];
    const float* lc1w   = (const float*)d_in[19];
    const float* bn3g   = (const float*)d_in[20];
    const float* bn3b   = (const float*)d_in[21];
    const float* bn3m   = (const float*)d_in[22];
    const float* bn3v   = (const float*)d_in[23];
    const float* lc2w   = (const float*)d_in[24];
    const float* bn4g   = (const float*)d_in[25];
    const float* bn4b   = (const float*)d_in[26];
    const float* bn4m   = (const float*)d_in[27];
    const float* bn4v   = (const float*)d_in[28];
    const float* fc1w   = (const float*)d_in[29];
    const float* fc1b   = (const float*)d_in[30];
    const float* bnf1g  = (const float*)d_in[31];
    const float* bnf1b  = (const float*)d_in[32];
    const float* bnf1m  = (const float*)d_in[33];
    const float* bnf1v  = (const float*)d_in[34];
    const float* fc2w   = (const float*)d_in[35];
    const float* fc2b   = (const float*)d_in[36];
    const float* bnf2g  = (const float*)d_in[37];
    const float* bnf2b  = (const float*)d_in[38];
    const float* bnf2m  = (const float*)d_in[39];
    const float* bnf2v  = (const float*)d_in[40];
    const float* fc3w   = (const float*)d_in[41];
    const float* fc3b   = (const float*)d_in[42];
    const float* bnf3g  = (const float*)d_in[43];
    const float* bnf3b  = (const float*)d_in[44];
    const float* bnf3m  = (const float*)d_in[45];
    const float* bnf3v  = (const float*)d_in[46];
    const float* outw   = (const float*)d_in[47];
    const float* outb   = (const float*)d_in[48];

    char* wsb = (char*)d_ws;
    __bf16* w1frag  = (__bf16*)wsb;                        // 2048 el
    __bf16* w2frag  = w1frag + 2048;                       // 36864 el
    __bf16* lc1frag = w2frag + 36864;                      // 524288 el
    __bf16* lc2frag = lc1frag + 524288;                    // 524288 el
    __bf16* fc1Wb   = lc2frag + 524288;                    // 4194304 el
    __bf16* wf23    = fc1Wb + 4194304;                     // 344064 el
    __bf16* act     = wf23 + 344064;                       // 12582912 el
    __bf16* act3    = act + 12582912;                      // 786432 el
    __bf16* act4    = act3 + 786432;                       // 786432 el
    float*  part    = (float*)(((uintptr_t)(act4 + 786432) + 15) & ~(uintptr_t)15);
    __bf16* wf2 = wf23;
    __bf16* wf3 = wf23 + 262144;
    __bf16* wfo = wf23 + 327680;

    MegaArgs ma;
    ma.inA = inA; ma.inP = inP; ma.inN = inN;
    ma.bn0g = bn0g; ma.bn0b = bn0b; ma.bn0m = bn0m; ma.bn0v = bn0v;
    ma.w1 = conv1w; ma.w2 = conv2w; ma.b1 = conv1b;
    ma.bn1g = bn1g; ma.bn1b = bn1b; ma.bn1m = bn1m; ma.bn1v = bn1v;
    ma.b2 = conv2b; ma.bn2g = bn2g; ma.bn2b = bn2b; ma.bn2m = bn2m; ma.bn2v = bn2v;
    ma.lc1 = lc1w; ma.lc2 = lc2w;
    ma.bn3g = bn3g; ma.bn3b = bn3b; ma.bn3m = bn3m; ma.bn3v = bn3v;
    ma.bn4g = bn4g; ma.bn4b = bn4b; ma.bn4m = bn4m; ma.bn4v = bn4v;
    ma.fc1w = fc1w; ma.fc1b = fc1b;
    ma.g1 = bnf1g; ma.bb1 = bnf1b; ma.m1 = bnf1m; ma.v1 = bnf1v;
    ma.fc2w = fc2w; ma.fc2b = fc2b;
    ma.g2 = bnf2g; ma.bb2 = bnf2b; ma.m2 = bnf2m; ma.v2 = bnf2v;
    ma.fc3w = fc3w; ma.fc3b = fc3b;
    ma.g3 = bnf3g; ma.bb3 = bnf3b; ma.m3 = bnf3m; ma.v3 = bnf3v;
    ma.outw = outw; ma.outb = outb;
    ma.w1frag = w1frag; ma.w2frag = w2frag;
    ma.lc1frag = lc1frag; ma.lc2frag = lc2frag;
    ma.fc1Wb = fc1Wb; ma.wf23 = wf23; ma.act = act; ma.act3 = act3;
    ma.part = part; ma.dout = (float*)d_out;

    void* kargs[] = { (void*)&ma };
    hipError_t err = hipLaunchCooperativeKernel((const void*)k_mega,
        dim3(GRID), dim3(256), kargs, 0, stream);

    if (err != hipSuccess) {
        (void)hipGetLastError();   // clear sticky error; fall back to 7-launch path
        k_prep_conv<<<19, 256, 0, stream>>>(conv1w, conv2w, w1frag, w2frag);
        k_conv_prep<<<3520, 256, 0, stream>>>(inA, inP, inN,
            bn0g, bn0b, bn0m, bn0v, w1frag, conv1b, bn1g, bn1b, bn1m, bn1v,
            w2frag, conv2b, bn2g, bn2b, bn2m, bn2v, act,
            lc1w, lc2w, fc1w, fc2w, fc3w, outw,
            lc1frag, lc2frag, fc1Wb, wf23);
        k_lc_mfma<<<dim3(128, 24), 256, 0, stream>>>(lc1frag, lc2frag,
            bn3g, bn3b, bn3m, bn3v, bn4g, bn4b, bn4m, bn4v, act);
        k_fc1_mfma<<<dim3(24, 4, 8), 256, 0, stream>>>(act, fc1Wb, part);
        k_fc1_reduce<<<768, 256, 0, stream>>>(part, fc1b, bnf1g, bnf1b, bnf1m, bnf1v, act3);
        k_fc2_mfma<<<dim3(24, 8), 256, 0, stream>>>(act3, wf2, fc2b,
            bnf2g, bnf2b, bnf2m, bnf2v, act4);
        k_fc3out<<<48, 256, 0, stream>>>(act4, wf3, wfo, fc3b,
            bnf3g, bnf3b, bnf3m, bnf3v, outb, (float*)d_out);
    }
}

// Round 10
// 253.128 us; speedup vs baseline: 5.3147x; 5.3147x over previous
//
#include <hip/hip_runtime.h>
#include <math.h>

#define EPS 1e-5f
#define FD 8192

typedef __attribute__((ext_vector_type(8))) __bf16 bf16x8;
typedef __attribute__((ext_vector_type(4))) float f32x4;

static __device__ __forceinline__ f32x4 mfma16(bf16x8 a, bf16x8 b, f32x4 c) {
    return __builtin_amdgcn_mfma_f32_16x16x32_bf16(a, b, c, 0, 0, 0);
}

// ========== K0: conv weight prep only (19 blocks, tiny) ======================
__global__ __launch_bounds__(256) void k_prep_conv(
    const float* __restrict__ w1, const float* __restrict__ w2,
    __bf16* __restrict__ w1frag, __bf16* __restrict__ w2frag) {
    const int bb = blockIdx.x;
    const int t = threadIdx.x;
    if (bb == 0) {
        const int lane = t & 63, w = t >> 6;
        const int q = lane >> 4, li = lane & 15;
        const int o = w * 16 + li;
        bf16x8 v;
#pragma unroll
        for (int j = 0; j < 8; ++j) {
            int k = q * 8 + j;
            v[j] = (k < 9) ? (__bf16)w1[o * 9 + k] : (__bf16)0.0f;
        }
        *(bf16x8*)(w1frag + t * 8) = v;
    } else {
        const int id = (bb - 1) * 256 + t;
        const int lane = id & 63;
        const int w = (id >> 6) & 3;
        const int chunk = (id >> 8) & 1;
        const int tap = id >> 9;
        const int q = lane >> 4, li = lane & 15;
        const int o = w * 16 + li;
        const int c0 = chunk * 32 + q * 8;
        bf16x8 v;
#pragma unroll
        for (int j = 0; j < 8; ++j)
            v[j] = (__bf16)w2[(o * 64 + c0 + j) * 9 + tap];
        *(bf16x8*)(w2frag + (size_t)id * 8) = v;
    }
}

// ========== K1: conv stage (blocks 0..1535) + remaining weight prep =========
// conv branch LDS 32.9KB (A1/im2col dropped; conv1 A-frags gathered directly
// from xpad). Measured r8: 42.2us, MfmaUtil 13.2, Occupancy 25.5.
__global__ __launch_bounds__(256) void k_conv_prep(
    const float* __restrict__ inA, const float* __restrict__ inP, const float* __restrict__ inN,
    const float* __restrict__ bn0g, const float* __restrict__ bn0b,
    const float* __restrict__ bn0m, const float* __restrict__ bn0v,
    const __bf16* __restrict__ w1frag, const float* __restrict__ b1,
    const float* __restrict__ bn1g, const float* __restrict__ bn1b,
    const float* __restrict__ bn1m, const float* __restrict__ bn1v,
    const __bf16* __restrict__ w2frag, const float* __restrict__ b2,
    const float* __restrict__ bn2g, const float* __restrict__ bn2b,
    const float* __restrict__ bn2m, const float* __restrict__ bn2v,
    __bf16* __restrict__ act,
    const float* __restrict__ lc1, const float* __restrict__ lc2,
    const float* __restrict__ fc1w, const float* __restrict__ fc2w,
    const float* __restrict__ fc3w, const float* __restrict__ outw,
    __bf16* __restrict__ lc1frag, __bf16* __restrict__ lc2frag,
    __bf16* __restrict__ fc1Wb, __bf16* __restrict__ wf23) {
    const int bb = blockIdx.x;
    const int t = threadIdx.x;
    __shared__ __align__(16) char smem[32896];

    if (bb >= 1536) {
        const int bx2 = bb - 1536;
        if (bx2 < 128) {
            // lc weights -> frag order; 2-pass LDS staging (stride 66)
            float (*wbuf)[66] = (float(*)[66])smem;
            const int layer = bx2 >> 6, o = bx2 & 63;
            const int wo = o >> 4, lo = o & 15;
            const float* src = (layer ? lc2 : lc1) + (size_t)o * 8192;
            __bf16* dst = layer ? lc2frag : lc1frag;
            for (int P = 0; P < 2; ++P) {
                if (P) __syncthreads();
#pragma unroll
                for (int it = 0; it < 4; ++it) {
                    int idx = it * 1024 + t * 4;
                    int c = idx >> 6, pp = idx & 63;
                    float4 v = *(const float4*)(src + c * 128 + P * 64 + pp);
                    wbuf[c][pp + 0] = v.x; wbuf[c][pp + 1] = v.y;
                    wbuf[c][pp + 2] = v.z; wbuf[c][pp + 3] = v.w;
                }
                __syncthreads();
#pragma unroll
                for (int it = 0; it < 2; ++it) {
                    int slot = it * 256 + t;
                    int pp = slot >> 3, chunk = (slot >> 2) & 1, q = slot & 3;
                    int p = P * 64 + pp;
                    bf16x8 v;
#pragma unroll
                    for (int j = 0; j < 8; ++j)
                        v[j] = (__bf16)wbuf[chunk * 32 + q * 8 + j][pp];
                    *(bf16x8*)(dst + ((size_t)((p * 2 + chunk) * 4 + wo) * 64 + q * 16 + lo) * 8) = v;
                }
            }
        } else if (bx2 < 640) {
            // fc1 weights -> bf16 [n][kA], kA = p*64+c; 2-pass staging
            float (*wbuf)[66] = (float(*)[66])smem;
            const int n = bx2 - 128;
            const float* src = fc1w + (size_t)n * 8192;
            __bf16* dst = fc1Wb + (size_t)n * 8192;
            for (int P = 0; P < 2; ++P) {
                if (P) __syncthreads();
#pragma unroll
                for (int it = 0; it < 4; ++it) {
                    int idx = it * 1024 + t * 4;
                    int c = idx >> 6, pp = idx & 63;
                    float4 v = *(const float4*)(src + c * 128 + P * 64 + pp);
                    wbuf[c][pp + 0] = v.x; wbuf[c][pp + 1] = v.y;
                    wbuf[c][pp + 2] = v.z; wbuf[c][pp + 3] = v.w;
                }
                __syncthreads();
#pragma unroll
                for (int it = 0; it < 8; ++it) {
                    int kA = P * 4096 + (it * 256 + t) * 2;
                    int c = kA & 63, pp = (kA >> 6) & 63;
                    __bf16 tmp[2];
                    tmp[0] = (__bf16)wbuf[c][pp];
                    tmp[1] = (__bf16)wbuf[c + 1][pp];
                    *(unsigned int*)(dst + kA) = *(unsigned int*)tmp;
                }
            }
        } else {
            int i = (bx2 - 640) * 256 + t;
            float v;
            if (i < 262144) v = fc2w[i];
            else if (i < 327680) v = fc3w[i - 262144];
            else v = outw[i - 327680];
            wf23[i] = (__bf16)v;
        }
        return;
    }

    // ---------------- conv path ----------------
    __bf16* Xp  = (__bf16*)smem;                     // 31104 B
    float* xpad = (float*)(smem + 31104);            // 768 B
    float* s1   = (float*)(smem + 31872);
    float* sh1  = (float*)(smem + 32128);
    float* s2   = (float*)(smem + 32384);
    float* sh2  = (float*)(smem + 32640);

    const int b = bb;
    const int lane = t & 63, w = t >> 6;
    const int q = lane >> 4, li = lane & 15;
    const int n0 = w * 16;
    const float* src = (b < 512 ? inA : (b < 1024 ? inP : inN)) + (size_t)(b & 511) * 128;

    bf16x8 w1f = *(const bf16x8*)(w1frag + (size_t)(w * 64 + lane) * 8);
    bf16x8 w2f[18];
#pragma unroll
    for (int tap = 0; tap < 9; ++tap)
#pragma unroll
        for (int ch = 0; ch < 2; ++ch)
            w2f[tap * 2 + ch] = *(const bf16x8*)(w2frag +
                ((size_t)((tap * 2 + ch) * 4 + w) * 64 + lane) * 8);

    {
        int* xz = (int*)Xp;
        for (int i = t; i < 7776; i += 256) xz[i] = 0;
        if (t < 180) xpad[t] = 0.f;
        if (t < 64) {
            float sa = bn1g[t] * rsqrtf(bn1v[t] + EPS);
            s1[t] = sa;
            sh1[t] = (b1[t] - bn1m[t]) * sa + bn1b[t];
            float sb = bn2g[t] * rsqrtf(bn2v[t] + EPS);
            s2[t] = sb;
            sh2[t] = (b2[t] - bn2m[t]) * sb + bn2b[t];
        }
    }
    __syncthreads();
    if (t < 128) {
        float s0 = bn0g[0] * rsqrtf(bn0v[0] + EPS);
        float v = (src[t] - bn0m[0]) * s0 + bn0b[0];
        xpad[((t >> 3) + 1) * 10 + (t & 7) + 1] = v;
    }
    __syncthreads();
    {   // conv1 MFMA, A-frag gathered directly from xpad (no im2col buffer)
        const float sco = s1[n0 + li], sho = sh1[n0 + li];
        const int o = n0 + li;
#pragma unroll
        for (int m = 0; m < 8; ++m) {
            const int p = m * 16 + li;
            const int r = p >> 3, cl = p & 7;
            bf16x8 a;
#pragma unroll
            for (int j = 0; j < 8; ++j) a[j] = (__bf16)0.f;
            if (q == 0) {
                const float* xb = xpad + r * 10 + cl;
                a[0] = (__bf16)xb[0];  a[1] = (__bf16)xb[1];  a[2] = (__bf16)xb[2];
                a[3] = (__bf16)xb[10]; a[4] = (__bf16)xb[11]; a[5] = (__bf16)xb[12];
                a[6] = (__bf16)xb[20]; a[7] = (__bf16)xb[21];
            } else if (q == 1) {
                a[0] = (__bf16)xpad[(r + 2) * 10 + cl + 2];
            }
            f32x4 z = {0.f, 0.f, 0.f, 0.f};
            f32x4 d = mfma16(a, w1f, z);
#pragma unroll
            for (int r2 = 0; r2 < 4; ++r2) {
                int pp = m * 16 + q * 4 + r2;
                float v = fmaxf(d[r2] * sco + sho, 0.f);
                Xp[(((pp >> 3) + 1) * 12 + (pp & 7) + 1) * 72 + o] = (__bf16)v;
            }
        }
    }
    __syncthreads();
    // conv2 implicit GEMM: accumulate ALL tiles in registers first
    f32x4 accA[4], accB[4];
#pragma unroll
    for (int i = 0; i < 4; ++i) {
        accA[i] = (f32x4){0.f, 0.f, 0.f, 0.f};
        accB[i] = (f32x4){0.f, 0.f, 0.f, 0.f};
    }
    {
        const int cl = li & 7;
#pragma unroll
        for (int mp = 0; mp < 4; ++mp) {
            const int r0 = mp * 4 + (li >> 3);
            const int base0 = (r0 * 12 + cl) * 72 + q * 8;
            const int base1 = base0 + 1728;               // +2 rows
#pragma unroll
            for (int tap = 0; tap < 9; ++tap) {
                const int tofs = ((tap / 3) * 12 + (tap % 3)) * 72;
#pragma unroll
                for (int ch = 0; ch < 2; ++ch) {
                    bf16x8 a0 = *(const bf16x8*)&Xp[base0 + tofs + ch * 32];
                    bf16x8 a1 = *(const bf16x8*)&Xp[base1 + tofs + ch * 32];
                    accA[mp] = mfma16(a0, w2f[tap * 2 + ch], accA[mp]);
                    accB[mp] = mfma16(a1, w2f[tap * 2 + ch], accB[mp]);
                }
            }
        }
    }
    __syncthreads();   // all Xp reads done; reuse as repack buffer (stride 72)
    {
        const float sco = s2[n0 + li], sho = sh2[n0 + li];
        const int o = n0 + li;
#pragma unroll
        for (int mp = 0; mp < 4; ++mp) {
#pragma unroll
            for (int r = 0; r < 4; ++r) {
                int p0 = mp * 32 + q * 4 + r;
                Xp[p0 * 72 + o] = (__bf16)fmaxf(accA[mp][r] * sco + sho, 0.f);
                Xp[(p0 + 16) * 72 + o] = (__bf16)fmaxf(accB[mp][r] * sco + sho, 0.f);
            }
        }
    }
    __syncthreads();
    {   // cooperative coalesced store: 64B per thread
        int p = t >> 1, half = t & 1;
        const __bf16* rp = Xp + p * 72 + half * 32;
        __bf16* ob = act + (size_t)b * FD + p * 64 + half * 32;
        bf16x8 v0 = *(const bf16x8*)rp;
        bf16x8 v1 = *(const bf16x8*)(rp + 8);
        bf16x8 v2 = *(const bf16x8*)(rp + 16);
        bf16x8 v3 = *(const bf16x8*)(rp + 24);
        *(bf16x8*)ob = v0;
        *(bf16x8*)(ob + 8) = v1;
        *(bf16x8*)(ob + 16) = v2;
        *(bf16x8*)(ob + 24) = v3;
    }
}

// ========== K2: lc1 + bn3relu + lc2 + bn4relu (MFMA, in-place) ===============
__global__ __launch_bounds__(256) void k_lc_mfma(
    const __bf16* __restrict__ lc1frag, const __bf16* __restrict__ lc2frag,
    const float* __restrict__ bn3g, const float* __restrict__ bn3b,
    const float* __restrict__ bn3m, const float* __restrict__ bn3v,
    const float* __restrict__ bn4g, const float* __restrict__ bn4b,
    const float* __restrict__ bn4m, const float* __restrict__ bn4v,
    __bf16* __restrict__ act) {
    const int p = blockIdx.x;
    const int b0 = blockIdx.y * 64;
    const int t = threadIdx.x;
    const int lane = t & 63, w = t >> 6;
    const int q = lane >> 4, li = lane & 15;
    const int n0 = w * 16;

    __shared__ __align__(16) __bf16 xs[64 * 72];
    __shared__ __align__(16) __bf16 ys[64 * 72];
    __shared__ float s3[64], sh3[64], s4[64], sh4[64];

    if (t < 64) {
        float sa = bn3g[t] * rsqrtf(bn3v[t] + EPS);
        s3[t] = sa; sh3[t] = bn3b[t] - bn3m[t] * sa;
        float sb = bn4g[t] * rsqrtf(bn4v[t] + EPS);
        s4[t] = sb; sh4[t] = bn4b[t] - bn4m[t] * sb;
    }
    {
        int s = t >> 2, cg = t & 3;
        const __bf16* rp = act + (size_t)(b0 + s) * FD + p * 64 + cg * 16;
        *(bf16x8*)&xs[s * 72 + cg * 16] = *(const bf16x8*)rp;
        *(bf16x8*)&xs[s * 72 + cg * 16 + 8] = *(const bf16x8*)(rp + 8);
    }
    bf16x8 w1a = *(const bf16x8*)(lc1frag + ((size_t)((p * 2 + 0) * 4 + w) * 64 + lane) * 8);
    bf16x8 w1b = *(const bf16x8*)(lc1frag + ((size_t)((p * 2 + 1) * 4 + w) * 64 + lane) * 8);
    bf16x8 w2a = *(const bf16x8*)(lc2frag + ((size_t)((p * 2 + 0) * 4 + w) * 64 + lane) * 8);
    bf16x8 w2b = *(const bf16x8*)(lc2frag + ((size_t)((p * 2 + 1) * 4 + w) * 64 + lane) * 8);
    __syncthreads();
    {   // layer 1 -> ys
        const float sco = s3[n0 + li], sho = sh3[n0 + li];
#pragma unroll
        for (int m = 0; m < 4; ++m) {
            bf16x8 a0 = *(const bf16x8*)&xs[(m * 16 + li) * 72 + q * 8];
            bf16x8 a1 = *(const bf16x8*)&xs[(m * 16 + li) * 72 + 32 + q * 8];
            f32x4 acc = {0.f, 0.f, 0.f, 0.f};
            acc = mfma16(a0, w1a, acc);
            acc = mfma16(a1, w1b, acc);
#pragma unroll
            for (int r = 0; r < 4; ++r) {
                int bl = m * 16 + q * 4 + r;
                ys[bl * 72 + n0 + li] = (__bf16)fmaxf(acc[r] * sco + sho, 0.f);
            }
        }
    }
    __syncthreads();
    {   // layer 2 -> xs (repack), then coalesced store
        const float sco = s4[n0 + li], sho = sh4[n0 + li];
#pragma unroll
        for (int m = 0; m < 4; ++m) {
            bf16x8 a0 = *(const bf16x8*)&ys[(m * 16 + li) * 72 + q * 8];
            bf16x8 a1 = *(const bf16x8*)&ys[(m * 16 + li) * 72 + 32 + q * 8];
            f32x4 acc = {0.f, 0.f, 0.f, 0.f};
            acc = mfma16(a0, w2a, acc);
            acc = mfma16(a1, w2b, acc);
#pragma unroll
            for (int r = 0; r < 4; ++r) {
                int bl = m * 16 + q * 4 + r;
                xs[bl * 72 + n0 + li] = (__bf16)fmaxf(acc[r] * sco + sho, 0.f);
            }
        }
    }
    __syncthreads();
    {
        int s = t >> 2, cg = t & 3;
        const __bf16* rp = xs + s * 72 + cg * 16;
        __bf16* ob = act + (size_t)(b0 + s) * FD + p * 64 + cg * 16;
        bf16x8 v0 = *(const bf16x8*)rp;
        bf16x8 v1 = *(const bf16x8*)(rp + 8);
        *(bf16x8*)ob = v0;
        *(bf16x8*)(ob + 8) = v1;
    }
}

// ========== K3: fc1 MFMA 64x128 tile, split-K 8, double-buffered LDS =========
__global__ __launch_bounds__(256) void k_fc1_mfma(
    const __bf16* __restrict__ A, const __bf16* __restrict__ Wb,
    float* __restrict__ part) {
    const int t = threadIdx.x;
    const int lane = t & 63, w = t >> 6;
    const int q = lane >> 4, li = lane & 15;
    const int m0 = blockIdx.x * 64, n0 = blockIdx.y * 128;
    const int k0 = blockIdx.z * 1024;
    const int wm = (w & 1) * 32, wn = (w >> 1) * 64;

    __shared__ __align__(16) __bf16 As[2][64 * 40];
    __shared__ __align__(16) __bf16 Bs[2][128 * 40];

    f32x4 acc[2][4];
#pragma unroll
    for (int i = 0; i < 2; ++i)
#pragma unroll
        for (int j = 0; j < 4; ++j) acc[i][j] = (f32x4){0.f, 0.f, 0.f, 0.f};

    const int rowA = (t & 127) >> 1, rowB = t >> 1, half = t & 1;
    const __bf16* Ag = A + (size_t)(m0 + rowA) * 8192 + k0 + half * 16;
    const __bf16* Bg = Wb + (size_t)(n0 + rowB) * 8192 + k0 + half * 16;

    bf16x8 pa0, pa1, pb0, pb1;
    pb0 = *(const bf16x8*)Bg;
    pb1 = *(const bf16x8*)(Bg + 8);
    if (t < 128) {
        pa0 = *(const bf16x8*)Ag;
        pa1 = *(const bf16x8*)(Ag + 8);
    }

    for (int step = 0; step < 32; ++step) {
        const int cur = step & 1;
        if (t < 128) {
            *(bf16x8*)&As[cur][rowA * 40 + half * 16] = pa0;
            *(bf16x8*)&As[cur][rowA * 40 + half * 16 + 8] = pa1;
        }
        *(bf16x8*)&Bs[cur][rowB * 40 + half * 16] = pb0;
        *(bf16x8*)&Bs[cur][rowB * 40 + half * 16 + 8] = pb1;
        __syncthreads();
        Ag += 32; Bg += 32;
        if (step < 31) {   // prefetch next chunk; overlaps MFMAs below
            pb0 = *(const bf16x8*)Bg;
            pb1 = *(const bf16x8*)(Bg + 8);
            if (t < 128) {
                pa0 = *(const bf16x8*)Ag;
                pa1 = *(const bf16x8*)(Ag + 8);
            }
        }
        bf16x8 af[2], bfr[4];
#pragma unroll
        for (int i = 0; i < 2; ++i)
            af[i] = *(const bf16x8*)&As[cur][(wm + i * 16 + li) * 40 + q * 8];
#pragma unroll
        for (int j = 0; j < 4; ++j)
            bfr[j] = *(const bf16x8*)&Bs[cur][(wn + j * 16 + li) * 40 + q * 8];
#pragma unroll
        for (int i = 0; i < 2; ++i)
#pragma unroll
            for (int j = 0; j < 4; ++j)
                acc[i][j] = mfma16(af[i], bfr[j], acc[i][j]);
        // no trailing barrier: next step writes the other buffer
    }
    float* pp = part + (size_t)blockIdx.z * 786432;
#pragma unroll
    for (int i = 0; i < 2; ++i) {
#pragma unroll
        for (int r = 0; r < 4; ++r) {
            int m = m0 + wm + i * 16 + q * 4 + r;
#pragma unroll
            for (int j = 0; j < 4; ++j) {
                int n = n0 + wn + j * 16 + li;
                pp[(size_t)m * 512 + n] = acc[i][j][r];
            }
        }
    }
}

// reduce 8 partials + bias + bn + relu -> bf16 act3
__global__ void k_fc1_reduce(const float* __restrict__ part, const float* __restrict__ bias,
                             const float* __restrict__ g, const float* __restrict__ bb,
                             const float* __restrict__ mm, const float* __restrict__ vv,
                             __bf16* __restrict__ out) {
    int gi = blockIdx.x * 256 + threadIdx.x;
    size_t off = (size_t)gi * 4;
    float4 s = make_float4(0.f, 0.f, 0.f, 0.f);
#pragma unroll
    for (int z = 0; z < 8; ++z) {
        float4 v = *(const float4*)(part + (size_t)z * 786432 + off);
        s.x += v.x; s.y += v.y; s.z += v.z; s.w += v.w;
    }
    int n = (gi & 127) * 4;
    float r[4] = {s.x, s.y, s.z, s.w};
    __bf16 o4[4];
#pragma unroll
    for (int j = 0; j < 4; ++j) {
        float sc = g[n + j] * rsqrtf(vv[n + j] + EPS);
        float x = (r[j] + bias[n + j] - mm[n + j]) * sc + bb[n + j];
        o4[j] = (__bf16)fmaxf(x, 0.f);
    }
    *(uint2*)(out + off) = *(uint2*)o4;
}

// ========= fc2: bf16 MFMA GEMM 64x64, fused bias/bn/relu, dbuf LDS ===========
__global__ __launch_bounds__(256) void k_fc2_mfma(
    const __bf16* __restrict__ A, const __bf16* __restrict__ W,
    const float* __restrict__ bias,
    const float* __restrict__ bng, const float* __restrict__ bnb,
    const float* __restrict__ bnm, const float* __restrict__ bnv,
    __bf16* __restrict__ out) {
    const int t = threadIdx.x;
    const int lane = t & 63, w = t >> 6;
    const int q = lane >> 4, li = lane & 15;
    const int m0 = blockIdx.x * 64, n0 = blockIdx.y * 64;
    const int wm = (w & 1) * 32, wn = (w >> 1) * 32;
    const int K = 512, N = 512;

    __shared__ __align__(16) __bf16 As[2][64 * 40];
    __shared__ __align__(16) __bf16 Bs[2][64 * 40];

    f32x4 acc[2][2];
#pragma unroll
    for (int i = 0; i < 2; ++i)
#pragma unroll
        for (int j = 0; j < 2; ++j) acc[i][j] = (f32x4){0.f, 0.f, 0.f, 0.f};

    const int row = (t & 127) >> 1, half = t & 1;
    const __bf16* g = (t < 128 ? A + (size_t)(m0 + row) * K
                               : W + (size_t)(n0 + row) * K) + half * 16;
    const int ldo = row * 40 + half * 16;

    bf16x8 p0 = *(const bf16x8*)g;
    bf16x8 p1 = *(const bf16x8*)(g + 8);
    for (int s = 0; s < 16; ++s) {
        const int cur = s & 1;
        __bf16* ld = (t < 128 ? As[cur] : Bs[cur]) + ldo;
        *(bf16x8*)ld = p0;
        *(bf16x8*)(ld + 8) = p1;
        __syncthreads();
        g += 32;
        if (s < 15) {
            p0 = *(const bf16x8*)g;
            p1 = *(const bf16x8*)(g + 8);
        }
        bf16x8 af[2], bfr[2];
#pragma unroll
        for (int i = 0; i < 2; ++i)
            af[i] = *(const bf16x8*)&As[cur][(wm + i * 16 + li) * 40 + q * 8];
#pragma unroll
        for (int j = 0; j < 2; ++j)
            bfr[j] = *(const bf16x8*)&Bs[cur][(wn + j * 16 + li) * 40 + q * 8];
#pragma unroll
        for (int i = 0; i < 2; ++i)
#pragma unroll
            for (int j = 0; j < 2; ++j)
                acc[i][j] = mfma16(af[i], bfr[j], acc[i][j]);
        // no trailing barrier (dbuf)
    }
    float bi[2], sc[2], hh[2];
#pragma unroll
    for (int j = 0; j < 2; ++j) {
        int n = n0 + wn + j * 16 + li;
        bi[j] = bias[n];
        sc[j] = bng[n] * rsqrtf(bnv[n] + EPS);
        hh[j] = bnb[n] - bnm[n] * sc[j];
    }
#pragma unroll
    for (int i = 0; i < 2; ++i) {
#pragma unroll
        for (int r = 0; r < 4; ++r) {
            int m = m0 + wm + i * 16 + q * 4 + r;
#pragma unroll
            for (int j = 0; j < 2; ++j) {
                int n = n0 + wn + j * 16 + li;
                float x = (acc[i][j][r] + bi[j]) * sc[j] + hh[j];
                out[(size_t)m * N + n] = (__bf16)fmaxf(x, 0.f);
            }
        }
    }
}

// ========= fused fc3 + bn + relu + out layer -> fp32 d_out ===================
// grid 48 blocks, 32 samples each; fc3: 32x128 K=512 (dbuf), out: 32x128 K=128
__global__ __launch_bounds__(256) void k_fc3out(
    const __bf16* __restrict__ A, const __bf16* __restrict__ W3,
    const __bf16* __restrict__ Wo,
    const float* __restrict__ b3,
    const float* __restrict__ bng, const float* __restrict__ bnb,
    const float* __restrict__ bnm, const float* __restrict__ bnv,
    const float* __restrict__ bo, float* __restrict__ out) {
    const int t = threadIdx.x;
    const int lane = t & 63, w = t >> 6;
    const int q = lane >> 4, li = lane & 15;
    const int m0 = blockIdx.x * 32;
    const int wn = w * 32;                 // wave covers 32 of N=128

    __shared__ __align__(16) __bf16 As[2][32 * 40];
    __shared__ __align__(16) __bf16 Bs[2][128 * 40];
    __shared__ __align__(16) __bf16 ysb[32 * 136];

    const int rowA = (t & 63) >> 1, rowB = t >> 1, half = t & 1;
    const __bf16* Ag = A + (size_t)(m0 + rowA) * 512 + half * 16;
    const __bf16* Bg = W3 + (size_t)rowB * 512 + half * 16;

    f32x4 acc[2][2];
#pragma unroll
    for (int i = 0; i < 2; ++i)
#pragma unroll
        for (int j = 0; j < 2; ++j) acc[i][j] = (f32x4){0.f, 0.f, 0.f, 0.f};

    bf16x8 pa0, pa1, pb0, pb1;
    pb0 = *(const bf16x8*)Bg;
    pb1 = *(const bf16x8*)(Bg + 8);
    if (t < 64) {
        pa0 = *(const bf16x8*)Ag;
        pa1 = *(const bf16x8*)(Ag + 8);
    }
    for (int step = 0; step < 16; ++step) {
        const int cur = step & 1;
        if (t < 64) {
            *(bf16x8*)&As[cur][rowA * 40 + half * 16] = pa0;
            *(bf16x8*)&As[cur][rowA * 40 + half * 16 + 8] = pa1;
        }
        *(bf16x8*)&Bs[cur][rowB * 40 + half * 16] = pb0;
        *(bf16x8*)&Bs[cur][rowB * 40 + half * 16 + 8] = pb1;
        __syncthreads();
        Ag += 32; Bg += 32;
        if (step < 15) {
            pb0 = *(const bf16x8*)Bg;
            pb1 = *(const bf16x8*)(Bg + 8);
            if (t < 64) {
                pa0 = *(const bf16x8*)Ag;
                pa1 = *(const bf16x8*)(Ag + 8);
            }
        }
        bf16x8 af[2], bfr[2];
#pragma unroll
        for (int i = 0; i < 2; ++i)
            af[i] = *(const bf16x8*)&As[cur][(i * 16 + li) * 40 + q * 8];
#pragma unroll
        for (int j = 0; j < 2; ++j)
            bfr[j] = *(const bf16x8*)&Bs[cur][(wn + j * 16 + li) * 40 + q * 8];
#pragma unroll
        for (int i = 0; i < 2; ++i)
#pragma unroll
            for (int j = 0; j < 2; ++j)
                acc[i][j] = mfma16(af[i], bfr[j], acc[i][j]);
        // no trailing barrier (dbuf)
    }
    __syncthreads();   // all K-loop LDS reads drained before Bs reuse below
    {   // fc3 epilogue -> ysb (bf16, stride 136)
#pragma unroll
        for (int j = 0; j < 2; ++j) {
            int n = wn + j * 16 + li;
            float sc = bng[n] * rsqrtf(bnv[n] + EPS);
            float hh = bnb[n] - bnm[n] * sc;
            float bi = b3[n];
#pragma unroll
            for (int i = 0; i < 2; ++i)
#pragma unroll
                for (int r = 0; r < 4; ++r) {
                    int ml = i * 16 + q * 4 + r;
                    float x = (acc[i][j][r] + bi) * sc + hh;
                    ysb[ml * 136 + n] = (__bf16)fmaxf(x, 0.f);
                }
        }
    }
    __syncthreads();
    // out layer: M=32, N=128, K=128 from ysb; 4 steps, dbuf Bs
    f32x4 acc2[2][2];
#pragma unroll
    for (int i = 0; i < 2; ++i)
#pragma unroll
        for (int j = 0; j < 2; ++j) acc2[i][j] = (f32x4){0.f, 0.f, 0.f, 0.f};
    const __bf16* Bg2 = Wo + (size_t)rowB * 128 + half * 16;
#pragma unroll
    for (int s = 0; s < 4; ++s) {
        const int cur = s & 1;
        *(bf16x8*)&Bs[cur][rowB * 40 + half * 16] = *(const bf16x8*)(Bg2 + s * 32);
        *(bf16x8*)&Bs[cur][rowB * 40 + half * 16 + 8] = *(const bf16x8*)(Bg2 + s * 32 + 8);
        __syncthreads();
        bf16x8 af[2], bfr[2];
#pragma unroll
        for (int i = 0; i < 2; ++i)
            af[i] = *(const bf16x8*)&ysb[(i * 16 + li) * 136 + s * 32 + q * 8];
#pragma unroll
        for (int j = 0; j < 2; ++j)
            bfr[j] = *(const bf16x8*)&Bs[cur][(wn + j * 16 + li) * 40 + q * 8];
#pragma unroll
        for (int i = 0; i < 2; ++i)
#pragma unroll
            for (int j = 0; j < 2; ++j)
                acc2[i][j] = mfma16(af[i], bfr[j], acc2[i][j]);
    }
#pragma unroll
    for (int j = 0; j < 2; ++j) {
        int n = wn + j * 16 + li;
        float bi = bo[n];
#pragma unroll
        for (int i = 0; i < 2; ++i)
#pragma unroll
            for (int r = 0; r < 4; ++r) {
                int m = m0 + i * 16 + q * 4 + r;
                out[(size_t)m * 128 + n] = acc2[i][j][r] + bi;
            }
    }
}

extern "C" void kernel_launch(void* const* d_in, const int* in_sizes, int n_in,
                              void* d_out, int out_size, void* d_ws, size_t ws_size,
                              hipStream_t stream) {
    const float* inA    = (const float*)d_in[0];
    const float* inP    = (const float*)d_in[1];
    const float* inN    = (const float*)d_in[2];
    const float* bn0g   = (const float*)d_in[3];
    const float* bn0b   = (const float*)d_in[4];
    const float* bn0m   = (const float*)d_in[5];
    const float* bn0v   = (const float*)d_in[6];
    const float* conv1w = (const float*)d_in[7];
    const float* conv1b = (const float*)d_in[8];
    const float* bn1g   = (const float*)d_in[9];
    const float* bn1b   = (const float*)d_in[10];
    const float* bn1m   = (const float*)d_in[11];
    const float* bn1v   = (const float*)d_in[12];
    const float* conv2w = (const float*)d_in[13];
    const float* conv2b = (const float*)d_in[14];
    const float* bn2g   = (const float*)d_in[15];
    const float* bn2b   = (const float*)d_in[16];
    const float* bn2m   = (const float*)d_in[17];
    const float* bn2v   = (const float*)d_in[18];
    const float* lc1w   = (const float*)d_in[19];
    const float* bn3g   = (const float*)d_in[20];
    const float* bn3b   = (const float*)d_in[21];
    const float* bn3m   = (const float*)d_in[22];
    const float* bn3v   = (const float*)d_in[23];
    const float* lc2w   = (const float*)d_in[24];
    const float* bn4g   = (const float*)d_in[25];
    const float* bn4b   = (const float*)d_in[26];
    const float* bn4m   = (const float*)d_in[27];
    const float* bn4v   = (const float*)d_in[28];
    const float* fc1w   = (const float*)d_in[29];
    const float* fc1b   = (const float*)d_in[30];
    const float* bnf1g  = (const float*)d_in[31];
    const float* bnf1b  = (const float*)d_in[32];
    const float* bnf1m  = (const float*)d_in[33];
    const float* bnf1v  = (const float*)d_in[34];
    const float* fc2w   = (const float*)d_in[35];
    const float* fc2b   = (const float*)d_in[36];
    const float* bnf2g  = (const float*)d_in[37];
    const float* bnf2b  = (const float*)d_in[38];
    const float* bnf2m  = (const float*)d_in[39];
    const float* bnf2v  = (const float*)d_in[40];
    const float* fc3w   = (const float*)d_in[41];
    const float* fc3b   = (const float*)d_in[42];
    const float* bnf3g  = (const float*)d_in[43];
    const float* bnf3b  = (const float*)d_in[44];
    const float* bnf3m  = (const float*)d_in[45];
    const float* bnf3v  = (const float*)d_in[46];
    const float* outw   = (const float*)d_in[47];
    const float* outb   = (const float*)d_in[48];

    char* wsb = (char*)d_ws;
    __bf16* w1frag  = (__bf16*)wsb;                        // 2048 el
    __bf16* w2frag  = w1frag + 2048;                       // 36864 el
    __bf16* lc1frag = w2frag + 36864;                      // 524288 el
    __bf16* lc2frag = lc1frag + 524288;                    // 524288 el
    __bf16* fc1Wb   = lc2frag + 524288;                    // 4194304 el
    __bf16* wf23    = fc1Wb + 4194304;                     // 344064 el
    __bf16* act     = wf23 + 344064;                       // 12582912 el
    __bf16* act3    = act + 12582912;                      // 786432 el
    __bf16* act4    = act3 + 786432;                       // 786432 el
    float*  part    = (float*)(((uintptr_t)(act4 + 786432) + 15) & ~(uintptr_t)15);
    __bf16* wf2 = wf23;
    __bf16* wf3 = wf23 + 262144;
    __bf16* wfo = wf23 + 327680;

    // ---- conv weight prep (tiny) ----
    k_prep_conv<<<19, 256, 0, stream>>>(conv1w, conv2w, w1frag, w2frag);

    // ---- conv stage + remaining weight prep (merged, independent blocks) ----
    k_conv_prep<<<3520, 256, 0, stream>>>(inA, inP, inN,
        bn0g, bn0b, bn0m, bn0v, w1frag, conv1b, bn1g, bn1b, bn1m, bn1v,
        w2frag, conv2b, bn2g, bn2b, bn2m, bn2v, act,
        lc1w, lc2w, fc1w, fc2w, fc3w, outw,
        lc1frag, lc2frag, fc1Wb, wf23);

    // ---- locally connected (in place, 64 samples/block) ----
    k_lc_mfma<<<dim3(128, 24), 256, 0, stream>>>(lc1frag, lc2frag,
        bn3g, bn3b, bn3m, bn3v, bn4g, bn4b, bn4m, bn4v, act);

    // ---- fc1 (split-K 8) + reduce ----
    k_fc1_mfma<<<dim3(24, 4, 8), 256, 0, stream>>>(act, fc1Wb, part);
    k_fc1_reduce<<<768, 256, 0, stream>>>(part, fc1b, bnf1g, bnf1b, bnf1m, bnf1v, act3);

    // ---- fc2 ----
    k_fc2_mfma<<<dim3(24, 8), 256, 0, stream>>>(act3, wf2, fc2b,
        bnf2g, bnf2b, bnf2m, bnf2v, act4);

    // ---- fc3 + out fused ----
    k_fc3out<<<48, 256, 0, stream>>>(act4, wf3, wfo, fc3b,
        bnf3g, bnf3b, bnf3m, bnf3v, outb, (float*)d_out);
}